// Round 6
// baseline (1025.504 us; speedup 1.0000x reference)
//
#include <hip/hip_runtime.h>
#include <math.h>

typedef __bf16 bf16;
typedef __bf16 bf16x8 __attribute__((ext_vector_type(8)));
typedef __bf16 bf16x4 __attribute__((ext_vector_type(4)));
typedef float f32x4 __attribute__((ext_vector_type(4)));

#define MFMA_B16(a,b,c) __builtin_amdgcn_mfma_f32_16x16x32_bf16((a),(b),(c),0,0,0)

constexpr int TMAXc = 30;
constexpr int Bc = 128, Pc = 196, Fc = 2048, Ec = 512, Hc = 1024, Vc = 10000;
constexpr int G4c = 4 * Hc;          // 4096
constexpr int NSTEP = TMAXc + 1;     // 31
constexpr int MALLc = NSTEP * Bc;    // 3968
constexpr int MOUTc = TMAXc * Bc;    // 3840
constexpr int NBLK = 256;            // persistent kernel grid

__device__ __forceinline__ float fsigm(float x){
  return __fdividef(1.0f, 1.0f + __expf(-x));
}
__device__ __forceinline__ float ftanh(float x){
  return 1.0f - __fdividef(2.0f, __expf(2.0f*x) + 1.0f);
}

__device__ __forceinline__ void gll16(const void* g, void* l){
  __builtin_amdgcn_global_load_lds((const __attribute__((address_space(1))) void*)g,
                                   (__attribute__((address_space(3))) void*)l, 16, 0, 0);
}

// 16B write-through store (bypasses L1/L2, lands at coherence point)
__device__ __forceinline__ void wt16(bf16* p, bf16x8 v){
  asm volatile("global_store_dwordx4 %0, %1, off sc0 sc1" :: "v"(p), "v"(v) : "memory");
}

// ---------------- prep kernels ----------------

// 256 blocks: (b, half). Each thread: 4 cols, float4 loads over 196 rows.
__global__ void mean_kernel(const float* __restrict__ enc, bf16* __restrict__ feat){
  int blk = blockIdx.x, b = blk >> 1, half = blk & 1;
  int f0 = half*1024 + threadIdx.x*4;
  const float* p = enc + (size_t)b*Pc*Fc + f0;
  float4 s = {0.f,0.f,0.f,0.f};
  #pragma unroll 4
  for (int q = 0; q < Pc; ++q) {
    float4 v = *(const float4*)(p + (size_t)q*Fc);
    s.x += v.x; s.y += v.y; s.z += v.z; s.w += v.w;
  }
  const float r = 1.0f/(float)Pc;
  bf16x4 o = { (bf16)(s.x*r), (bf16)(s.y*r), (bf16)(s.z*r), (bf16)(s.w*r) };
  *(bf16x4*)&feat[b*Fc + f0] = o;
}

__global__ void conv_kernel(const float* __restrict__ src, bf16* __restrict__ dst, int n4){
  int i = blockIdx.x*256 + threadIdx.x;
  if (i >= n4) return;
  float4 v = ((const float4*)src)[i];
  bf16x4 o = { (bf16)v.x, (bf16)v.y, (bf16)v.z, (bf16)v.w };
  *(bf16x4*)&dst[i*4] = o;
}

// W_ih (4096,512) -> permuted rows: row' = j*4+g  <-  row g*1024+j ; plain bf16
__global__ void permconv_ih(const float* __restrict__ W, bf16* __restrict__ Wp){
  int i = blockIdx.x*256 + threadIdx.x;
  if (i >= G4c*Ec/4) return;
  int i4 = i*4;
  int rp = i4 >> 9, k = i4 & 511;
  int g = rp & 3, j = rp >> 2;
  float4 v = *(const float4*)&W[(size_t)(g*Hc + j)*Ec + k];
  bf16x4 o = { (bf16)v.x, (bf16)v.y, (bf16)v.z, (bf16)v.w };
  *(bf16x4*)&Wp[i4] = o;
}

// W_hh (4096,1024) -> permuted + split hi/lo
__global__ void permsplit_hh(const float* __restrict__ W, bf16* __restrict__ Whi, bf16* __restrict__ Wlo){
  int i = blockIdx.x*256 + threadIdx.x;
  if (i >= G4c*Hc/4) return;
  int i4 = i*4;
  int rp = i4 >> 10, k = i4 & 1023;
  int g = rp & 3, j = rp >> 2;
  float4 v = *(const float4*)&W[(size_t)(g*Hc + j)*Hc + k];
  bf16 h0=(bf16)v.x, h1=(bf16)v.y, h2=(bf16)v.z, h3=(bf16)v.w;
  bf16x4 hi = { h0, h1, h2, h3 };
  bf16x4 lo = { (bf16)(v.x-(float)h0), (bf16)(v.y-(float)h1), (bf16)(v.z-(float)h2), (bf16)(v.w-(float)h3) };
  *(bf16x4*)&Whi[i4] = hi;
  *(bf16x4*)&Wlo[i4] = lo;
}

__global__ void split_kernel(const float* __restrict__ W, bf16* __restrict__ Whi, bf16* __restrict__ Wlo, int n4){
  int i = blockIdx.x*256 + threadIdx.x;
  if (i >= n4) return;
  float4 v = ((const float4*)W)[i];
  bf16 h0=(bf16)v.x, h1=(bf16)v.y, h2=(bf16)v.z, h3=(bf16)v.w;
  bf16x4 hi = { h0, h1, h2, h3 };
  bf16x4 lo = { (bf16)(v.x-(float)h0), (bf16)(v.y-(float)h1), (bf16)(v.z-(float)h2), (bf16)(v.w-(float)h3) };
  *(bf16x4*)&Whi[i*4] = hi;
  *(bf16x4*)&Wlo[i*4] = lo;
}

__global__ void bcomb_kernel(const float* __restrict__ bih, const float* __restrict__ bhh, float* __restrict__ bc){
  int i = blockIdx.x*256 + threadIdx.x;
  if (i >= G4c) return;
  int g = i & 3, j = i >> 2;
  bc[i] = bih[g*Hc + j] + bhh[g*Hc + j];
}

// embedding gather into X_all rows 128..3967 (row = s*128+b holds x_s = emb_{s-1})
__global__ void gather_kernel(const float* __restrict__ emb, const int* __restrict__ gt, bf16* __restrict__ X){
  int idx = blockIdx.x*256 + threadIdx.x;
  if (idx >= MOUTc*(Ec/4)) return;
  int r = idx >> 7, ei = (idx & 127) * 4;
  int s = (r >> 7) + 1, b = r & 127;
  int tok = gt[b*(TMAXc+1) + (s-1)];
  float4 v = *(const float4*)(emb + (size_t)tok*Ec + ei);
  bf16x4 o = { (bf16)v.x, (bf16)v.y, (bf16)v.z, (bf16)v.w };
  *(bf16x4*)&X[(size_t)(s*Bc + b)*Ec + ei] = o;
}

// valid-row index build: meta[0]=R, meta[1+i]=row id (t*128+b), t-major, padded w/ 0
__global__ void build_ridx(const int* __restrict__ lens, int* __restrict__ meta){
  int i = blockIdx.x*256 + threadIdx.x;
  if (i >= MOUTc) return;
  int t = i >> 7, b = i & 127;
  int S = 0, R = 0;
  for (int bb = 0; bb < 128; ++bb) {
    int l = lens[bb] - 1;
    S += (t < l) ? t : l;
    R += l;
  }
  if (i == 0) meta[0] = R;
  if (i >= R) meta[1 + i] = 0;
  if (t < lens[b] - 1) meta[1 + S + b] = i;
}

// zero the masked output rows (valid rows are written by the FC GEMM)
__global__ void zerofill(const int* __restrict__ lens, float* __restrict__ out){
  int i = blockIdx.x*256 + threadIdx.x;
  if (i >= MOUTc*2500) return;
  int row = i / 2500, c4 = i - row*2500;
  int b = row / TMAXc, t = row - b*TMAXc;
  if (t >= lens[b] - 1) {
    float4 z = {0.f,0.f,0.f,0.f};
    *(float4*)(out + (size_t)row*Vc + c4*4) = z;
  }
}

// ---------------- generic MFMA GEMM (128x128 tile, BK=32, nt-major, XCD swizzle) --------
// C[m,n] = sum_k A[m,k]*B[n,k]  (B is N x K row-major).
// EPI: 0 = x0 (sigmoid+BN), 1 = Xg (bias), 2 = FC (compacted rows via meta, bias, scatter)
template<int EPI, bool SPLIT, bool XSWZ>
__global__ __launch_bounds__(256, 2) void gemm_kernel(
  const bf16* __restrict__ Ahi, const bf16* __restrict__ Alo,
  const bf16* __restrict__ Bhi, const bf16* __restrict__ Blo,
  int M, int N, int K, int mtiles,
  const float* __restrict__ p0, const float* __restrict__ p1, const float* __restrict__ p2,
  bf16* __restrict__ outb, float* __restrict__ outf, const int* __restrict__ meta)
{
  constexpr int BK = 32;
  __shared__ alignas(16) bf16 sAh[128*BK], sBh[128*BK];
  __shared__ alignas(16) bf16 sAl[SPLIT ? 128*BK : 8], sBl[SPLIT ? 128*BK : 8];

  int tid = threadIdx.x;
  int lane = tid & 63, w = tid >> 6, wr = w >> 1, wc = w & 1;
  int bid = blockIdx.x;
  if constexpr (XSWZ) {
    // bijective XCD swizzle (m204): same-nt blocks land on one XCD's L2
    int nwg = gridDim.x, q = nwg >> 3, r = nwg & 7;
    int x = bid & 7, o = bid >> 3;
    bid = (x < r ? x*(q+1) : r*(q+1) + (x-r)*q) + o;
  }
  int nt = bid / mtiles, mt = bid - nt*mtiles;   // nt-major: B panel reused across consecutive blocks
  int m0 = mt*128, n0 = nt*128;

  int R = M;
  if constexpr (EPI == 2) {
    R = meta[0];
    if (m0 >= R) return;
  }

  // staging source rows (fixed per thread across the K loop)
  int sr = (tid*16) >> 6;            // 0..63
  int gr0, gr1;
  if constexpr (EPI == 2) { gr0 = meta[1 + m0 + sr]; gr1 = meta[1 + m0 + sr + 64]; }
  else                    { gr0 = m0 + sr;           gr1 = m0 + sr + 64; }

  f32x4 acc[4][4] = {};

  for (int kt = 0; kt < K; kt += BK) {
    #pragma unroll
    for (int is = 0; is < 2; ++is) {
      int p = tid*16 + is*4096;          // byte offset in 8KB tile
      int r = p >> 6, c = (p & 63) >> 1; // row, elem-col
      int ldsoff = w*512 + is*2048;      // elems (wave-uniform base)
      int ga = is ? gr1 : gr0;
      gll16(Ahi + (size_t)ga*K + kt + c, &sAh[ldsoff]);
      int rb = n0 + r; rb = rb < N ? rb : N - 1;
      gll16(Bhi + (size_t)rb*K + kt + c, &sBh[ldsoff]);
      if constexpr (SPLIT) {
        gll16(Alo + (size_t)ga*K + kt + c, &sAl[ldsoff]);
        gll16(Blo + (size_t)rb*K + kt + c, &sBl[ldsoff]);
      }
    }
    __syncthreads();

    int koff = (lane >> 4) * 8;
    bf16x8 ah[4], bh[4], al[SPLIT?4:1], bl[SPLIT?4:1];
    #pragma unroll
    for (int mi = 0; mi < 4; ++mi) {
      int rr = wr*64 + mi*16 + (lane & 15);
      ah[mi] = *(const bf16x8*)&sAh[rr*BK + koff];
      if constexpr (SPLIT) al[mi] = *(const bf16x8*)&sAl[rr*BK + koff];
    }
    #pragma unroll
    for (int ni = 0; ni < 4; ++ni) {
      int rr = wc*64 + ni*16 + (lane & 15);
      bh[ni] = *(const bf16x8*)&sBh[rr*BK + koff];
      if constexpr (SPLIT) bl[ni] = *(const bf16x8*)&sBl[rr*BK + koff];
    }
    #pragma unroll
    for (int mi = 0; mi < 4; ++mi)
      #pragma unroll
      for (int ni = 0; ni < 4; ++ni) {
        acc[mi][ni] = MFMA_B16(ah[mi], bh[ni], acc[mi][ni]);
        if constexpr (SPLIT) {
          acc[mi][ni] = MFMA_B16(ah[mi], bl[ni], acc[mi][ni]);
          acc[mi][ni] = MFMA_B16(al[mi], bh[ni], acc[mi][ni]);
        }
      }
    __syncthreads();
  }

  const float rbn = rsqrtf(1.0f + 1e-5f);
  #pragma unroll
  for (int mi = 0; mi < 4; ++mi) {
    #pragma unroll
    for (int ni = 0; ni < 4; ++ni) {
      int lrow = m0 + wr*64 + mi*16 + ((lane >> 4) << 2);
      int col = n0 + wc*64 + ni*16 + (lane & 15);
      #pragma unroll
      for (int j = 0; j < 4; ++j) {
        int rr = lrow + j;
        float v = acc[mi][ni][j];
        if constexpr (EPI == 0) {
          v = fsigm(v + p0[col]);
          v = p1[col]*(v*rbn) + p2[col];
          outb[(size_t)rr*Ec + col] = (bf16)v;
        } else if constexpr (EPI == 1) {
          outb[(size_t)rr*G4c + col] = (bf16)(v + p0[col]);
        } else {
          if (rr < R && col < N) {
            int val = meta[1 + rr];
            int t = val >> 7, b = val & 127;
            outf[(size_t)b*(TMAXc*Vc) + (size_t)t*Vc + col] = v + p0[col];
          }
        }
      }
    }
  }
}

// ---------------- persistent LSTM recurrence ----------------
// 256 blocks x 256 threads, 1 block/CU. Block (strip,rh):
// strip owns pcols [strip*32,+32) (= hcols [strip*8,+8)), rh owns rows [rh*64,+64).
// h chain layout: [slot][c8 128][rh 2][row 64][8 cols] bf16 (hi and lo buffers).
// Producer: epilogue -> 2KB LDS scratch -> coalesced 16B sc0sc1 write-through stores.
// Consumer: plain cached 16B loads (slot addresses fresh per step; L2 broadcast per XCD).

__device__ __forceinline__ void gridbar(int* cnt, int tgt){
  __syncthreads();                 // drains vmcnt(0): all write-through h stores committed
  if (threadIdx.x == 0) {
    __hip_atomic_fetch_add(cnt, 1, __ATOMIC_RELAXED, __HIP_MEMORY_SCOPE_AGENT);
    while (__hip_atomic_load(cnt, __ATOMIC_RELAXED, __HIP_MEMORY_SCOPE_AGENT) < tgt)
      __builtin_amdgcn_s_sleep(1);
  }
  __syncthreads();
}

__global__ __launch_bounds__(256, 1) void lstm_persist(
  const bf16* __restrict__ Whi, const bf16* __restrict__ Wlo, // [4096][1024] permuted
  const bf16* __restrict__ Xg,                                 // [31*128][4096]
  bf16* __restrict__ hCh, bf16* __restrict__ hCl,              // chains, slot0 zeroed
  bf16* __restrict__ Hh, bf16* __restrict__ Hl,                // [3840][1024]
  const int* __restrict__ lens,
  int* __restrict__ cnt)                                       // cnt[0]: rh0, cnt[64]: rh1
{
  extern __shared__ char sWc[];    // 128 KB W (hi at 0, lo at +65536, swizzled) + 2 KB scratch
  int tid = threadIdx.x, lane = tid & 63, w = tid >> 6;
  int bid = blockIdx.x;
  int strip = bid >> 1, rh = bid & 1;
  int pc0 = strip * 32;
  int row0 = rh * 64 + w * 16;
  int* mycnt = cnt + rh * 64;
  char* scr = sWc + 131072;        // 2 KB: hi [64][8] at 0, lo at +1024

  // ---- fill W slice into LDS (one-time), swizzle byte ^= (p&7)<<4 ----
  for (int ch = tid; ch < 4096; ch += 256) {
    int p = ch >> 7;             // 0..31
    int k = (ch & 127) * 8;      // 0..1016
    bf16x8 vh = *(const bf16x8*)&Whi[(size_t)(pc0 + p)*Hc + k];
    bf16x8 vl = *(const bf16x8*)&Wlo[(size_t)(pc0 + p)*Hc + k];
    int be = (p*Hc + k)*2;
    int sw = (p & 7) << 4;
    *(bf16x8*)(sWc + (be ^ sw)) = vh;
    *(bf16x8*)(sWc + ((be + 65536) ^ sw)) = vl;
  }
  __syncthreads();

  int bp = lane & 15;            // frag row/col within 16
  int bk = (lane >> 4) << 3;     // frag k offset
  int bswz = (bp & 7) << 4;
  int rbase = row0 + ((lane >> 4) << 2);
  int e = lane & 3;
  int bk8 = bk >> 3;             // 0..3
  int rihc = (w << 4) + bp;      // consumer row-in-half

  float creg[2][4] = {};
  float xgv[2][4];
  #pragma unroll
  for (int ni = 0; ni < 2; ++ni)
    #pragma unroll
    for (int j = 0; j < 4; ++j)
      xgv[ni][j] = (float)Xg[(size_t)(rbase + j)*G4c + pc0 + ni*16 + bp];

  #pragma unroll 1
  for (int s = 0; s < NSTEP; ++s) {
    // consumer base: slot s, c8 = ks*4 + bk8, own rh half, row rihc
    const bf16* pah = hCh + (size_t)s*Bc*Hc + ((size_t)((bk8*2 + rh)*64 + rihc))*8;
    const bf16* pal = hCl + (size_t)s*Bc*Hc + ((size_t)((bk8*2 + rh)*64 + rihc))*8;
    bf16* hwh = hCh + (size_t)(s+1)*Bc*Hc;
    bf16* hwl = hCl + (size_t)(s+1)*Bc*Hc;

    f32x4 aHH[2], aHL[2], aLH[2];
    #pragma unroll
    for (int ni = 0; ni < 2; ++ni) {
      #pragma unroll
      for (int j = 0; j < 4; ++j) aHH[ni][j] = xgv[ni][j];
      aHL[ni] = (f32x4){0.f,0.f,0.f,0.f};
      aLH[ni] = (f32x4){0.f,0.f,0.f,0.f};
    }

    #pragma unroll
    for (int ks = 0; ks < 32; ++ks) {
      bf16x8 avh = *(const bf16x8*)(pah + ks*4096);   // cached 16B load, 8KB stride
      bf16x8 avl = *(const bf16x8*)(pal + ks*4096);
      #pragma unroll
      for (int ni = 0; ni < 2; ++ni) {
        int be = ((ni*16 + bp)*Hc + ks*32 + bk)*2;
        bf16x8 bvh = *(const bf16x8*)(sWc + (be ^ bswz));
        bf16x8 bvl = *(const bf16x8*)(sWc + ((be + 65536) ^ bswz));
        aHH[ni] = MFMA_B16(avh, bvh, aHH[ni]);
        aHL[ni] = MFMA_B16(avh, bvl, aHL[ni]);
        aLH[ni] = MFMA_B16(avl, bvh, aLH[ni]);
      }
    }

    // ---- LSTM epilogue: combine 4 gates across lane-quads; drop hi/lo into LDS ----
    #pragma unroll
    for (int ni = 0; ni < 2; ++ni) {
      #pragma unroll
      for (int j = 0; j < 4; ++j) {
        float v = aHH[ni][j] + aHL[ni][j] + aLH[ni][j];
        float a  = v;
        float b1 = __shfl_xor(v, 1);
        float c2 = __shfl_xor(v, 2);
        float d3 = __shfl_xor(v, 3);
        int m;
        m = e;     float gI = (m==0)?a:(m==1)?b1:(m==2)?c2:d3;
        m = e ^ 1; float gF = (m==0)?a:(m==1)?b1:(m==2)?c2:d3;
        m = e ^ 2; float gG = (m==0)?a:(m==1)?b1:(m==2)?c2:d3;
        m = e ^ 3; float gO = (m==0)?a:(m==1)?b1:(m==2)?c2:d3;

        float co = creg[ni][j];
        float cn = fsigm(gF)*co + fsigm(gI)*ftanh(gG);
        float hn = fsigm(gO)*ftanh(cn);
        creg[ni][j] = cn;
        bf16 hhi = (bf16)hn;
        int rih = (w << 4) + ((lane >> 4) << 2) + j;   // row in half 0..63
        int cis = ni*4 + (bp >> 2);                    // col in strip 0..7
        if (e == 0)      *(bf16*)(scr + (rih*8 + cis)*2) = hhi;
        else if (e == 1) *(bf16*)(scr + 1024 + (rih*8 + cis)*2) = (bf16)(hn - (float)hhi);
      }
    }
    __syncthreads();

    // ---- wide store phase: 128 threads re-emit the 2KB slice coalesced ----
    if (tid < 128) {
      int c = tid & 63, buf = tid >> 6;                // buf 0 = hi, 1 = lo
      bf16x8 vv = *(const bf16x8*)(scr + buf*1024 + c*16);
      bf16* cd = (buf ? hwl : hwh) + ((size_t)((strip*2 + rh)*64 + c))*8;
      wt16(cd, vv);                                    // 16B write-through to chain
      if (s > 0) {
        int rrg = rh*64 + c;                           // global batch row
        if (s - 1 < lens[rrg] - 1) {                   // only rows the mask keeps
          *(bf16x8*)((buf ? Hl : Hh) + (size_t)((s-1)*Bc + rrg)*Hc + strip*8) = vv;
        }
      }
    }

    // prefetch next step's Xg before the barrier (independent of h)
    if (s + 1 < NSTEP) {
      #pragma unroll
      for (int ni = 0; ni < 2; ++ni)
        #pragma unroll
        for (int j = 0; j < 4; ++j)
          xgv[ni][j] = (float)Xg[(size_t)((s+1)*Bc + rbase + j)*G4c + pc0 + ni*16 + bp];
    }

    if (s < NSTEP - 1) gridbar(mycnt, (s + 1) * 128);
  }
}

// ---------------- launch ----------------

extern "C" void kernel_launch(void* const* d_in, const int* in_sizes, int n_in,
                              void* d_out, int out_size, void* d_ws, size_t ws_size,
                              hipStream_t stream)
{
  const float* enc   = (const float*)d_in[0];
  const int*   gt    = (const int*)  d_in[1];
  const int*   lens  = (const int*)  d_in[2];
  const float* emb   = (const float*)d_in[3];
  const float* Winit = (const float*)d_in[4];
  const float* binit = (const float*)d_in[5];
  const float* gam   = (const float*)d_in[6];
  const float* bet   = (const float*)d_in[7];
  const float* Wih   = (const float*)d_in[8];
  const float* bih   = (const float*)d_in[9];
  const float* Whh   = (const float*)d_in[10];
  const float* bhh   = (const float*)d_in[11];
  const float* Wfc   = (const float*)d_in[12];
  const float* bfc   = (const float*)d_in[13];
  float* out = (float*)d_out;

  char* ws = (char*)d_ws;
  size_t off = 0;
  auto alloc = [&](size_t bytes) -> char* {
    char* p = ws + off;
    off += (bytes + 255) & ~(size_t)255;
    return p;
  };

  bf16* featB  = (bf16*)alloc((size_t)Bc*Fc*2);
  bf16* WinitB = (bf16*)alloc((size_t)Ec*Fc*2);
  bf16* WihpB  = (bf16*)alloc((size_t)G4c*Ec*2);
  bf16* WhhHi  = (bf16*)alloc((size_t)G4c*Hc*2);
  bf16* WhhLo  = (bf16*)alloc((size_t)G4c*Hc*2);
  bf16* WfcHi  = (bf16*)alloc((size_t)Vc*Hc*2);
  bf16* WfcLo  = (bf16*)alloc((size_t)Vc*Hc*2);
  float* bcomb = (float*)alloc((size_t)G4c*4);
  bf16* Xall   = (bf16*)alloc((size_t)MALLc*Ec*2);
  bf16* Xg     = (bf16*)alloc((size_t)MALLc*G4c*2);
  bf16* hChH   = (bf16*)alloc((size_t)(NSTEP+1)*Bc*Hc*2);  // 32-slot chain
  bf16* hChL   = (bf16*)alloc((size_t)(NSTEP+1)*Bc*Hc*2);
  bf16* HallH  = (bf16*)alloc((size_t)MOUTc*Hc*2);
  bf16* HallL  = (bf16*)alloc((size_t)MOUTc*Hc*2);
  int*  meta   = (int*) alloc((size_t)(1 + MOUTc)*4);
  int*  cnt    = (int*) alloc((size_t)128*4);

  if (off > ws_size) return;

  // zero initial state + barrier counters (captured in graph -> re-done every replay)
  hipMemsetAsync(hChH, 0, (size_t)Bc*Hc*2, stream);
  hipMemsetAsync(hChL, 0, (size_t)Bc*Hc*2, stream);
  hipMemsetAsync(cnt, 0, (size_t)128*4, stream);

  // prep
  mean_kernel<<<256, 256, 0, stream>>>(enc, featB);
  conv_kernel<<<(Ec*Fc/4 + 255)/256, 256, 0, stream>>>(Winit, WinitB, Ec*Fc/4);
  permconv_ih<<<(G4c*Ec/4 + 255)/256, 256, 0, stream>>>(Wih, WihpB);
  permsplit_hh<<<(G4c*Hc/4 + 255)/256, 256, 0, stream>>>(Whh, WhhHi, WhhLo);
  split_kernel<<<(Vc*Hc/4 + 255)/256, 256, 0, stream>>>(Wfc, WfcHi, WfcLo, Vc*Hc/4);
  bcomb_kernel<<<(G4c + 255)/256, 256, 0, stream>>>(bih, bhh, bcomb);
  gather_kernel<<<(MOUTc*(Ec/4) + 255)/256, 256, 0, stream>>>(emb, gt, Xall);
  build_ridx<<<(MOUTc + 255)/256, 256, 0, stream>>>(lens, meta);
  zerofill<<<(MOUTc*2500 + 255)/256, 256, 0, stream>>>(lens, out);

  // GEMM A: x0 = sigmoid(feat @ Winit^T + b) * BN -> X_all rows 0..127
  gemm_kernel<0,false,false><<<4, 256, 0, stream>>>(
      featB, nullptr, WinitB, nullptr, Bc, Ec, Fc, 1,
      binit, gam, bet, Xall, nullptr, nullptr);

  // GEMM C: Xg = X_all @ Wihp^T + bcomb   (3968 x 4096, K=512), nt-major + XCD swizzle
  gemm_kernel<1,false,true><<<31*32, 256, 0, stream>>>(
      Xall, nullptr, WihpB, nullptr, MALLc, G4c, Ec, 31,
      bcomb, nullptr, nullptr, Xg, nullptr, nullptr);

  // recurrence: one persistent kernel, 31 steps
  hipFuncSetAttribute(reinterpret_cast<const void*>(lstm_persist),
                      hipFuncAttributeMaxDynamicSharedMemorySize, 133120);
  lstm_persist<<<NBLK, 256, 133120, stream>>>(
      WhhHi, WhhLo, Xg, hChH, hChL, HallH, HallL, lens, cnt);

  // GEMM E: preds = Hall[compacted] @ Wfc^T + b_fc -> scatter to out (split-3 + XCD swizzle)
  gemm_kernel<2,true,true><<<79*30, 256, 0, stream>>>(
      HallH, HallL, WfcHi, WfcLo, MOUTc, Vc, Hc, 30,
      bfc, nullptr, nullptr, nullptr, out, meta);
}

// Round 8
// 777.078 us; speedup vs baseline: 1.3197x; 1.3197x over previous
//
#include <hip/hip_runtime.h>
#include <math.h>

typedef __bf16 bf16;
typedef __bf16 bf16x8 __attribute__((ext_vector_type(8)));
typedef __bf16 bf16x4 __attribute__((ext_vector_type(4)));
typedef float f32x4 __attribute__((ext_vector_type(4)));

#define MFMA_B16(a,b,c) __builtin_amdgcn_mfma_f32_16x16x32_bf16((a),(b),(c),0,0,0)

constexpr int TMAXc = 30;
constexpr int Bc = 128, Pc = 196, Fc = 2048, Ec = 512, Hc = 1024, Vc = 10000;
constexpr int G4c = 4 * Hc;          // 4096
constexpr int NSTEP = TMAXc + 1;     // 31
constexpr int MALLc = NSTEP * Bc;    // 3968
constexpr int MOUTc = TMAXc * Bc;    // 3840
constexpr int NBLK = 256;            // persistent kernel grid

__device__ __forceinline__ float fsigm(float x){
  return __fdividef(1.0f, 1.0f + __expf(-x));
}
__device__ __forceinline__ float ftanh(float x){
  return 1.0f - __fdividef(2.0f, __expf(2.0f*x) + 1.0f);
}

__device__ __forceinline__ void gll16(const void* g, void* l){
  __builtin_amdgcn_global_load_lds((const __attribute__((address_space(1))) void*)g,
                                   (__attribute__((address_space(3))) void*)l, 16, 0, 0);
}

// 2B agent-scope write-through store (h goes to MALL; no fence/invalidate needed)
__device__ __forceinline__ void ast2(bf16* p, bf16 v){
  unsigned short b = __builtin_bit_cast(unsigned short, v);
  __hip_atomic_store((unsigned short*)p, b, __ATOMIC_RELAXED, __HIP_MEMORY_SCOPE_AGENT);
}

// bounded spin: escapes after ~2ms (s_memrealtime = 100 MHz const clock).
// Healthy runs resolve in ~us; the bound converts any protocol bug into a
// visible validation failure instead of a GPU hang.
__device__ __forceinline__ void waitflag(int* f, int tgt){
  long long t0 = __builtin_amdgcn_s_memrealtime();
  while (__hip_atomic_load(f, __ATOMIC_RELAXED, __HIP_MEMORY_SCOPE_AGENT) < tgt) {
    __builtin_amdgcn_s_sleep(1);
    if (__builtin_amdgcn_s_memrealtime() - t0 > 200000) break;
  }
}

// ---------------- prep kernels ----------------

// 256 blocks: (b, half). Each thread: 4 cols, float4 loads over 196 rows.
__global__ void mean_kernel(const float* __restrict__ enc, bf16* __restrict__ feat){
  int blk = blockIdx.x, b = blk >> 1, half = blk & 1;
  int f0 = half*1024 + threadIdx.x*4;
  const float* p = enc + (size_t)b*Pc*Fc + f0;
  float4 s = {0.f,0.f,0.f,0.f};
  #pragma unroll 4
  for (int q = 0; q < Pc; ++q) {
    float4 v = *(const float4*)(p + (size_t)q*Fc);
    s.x += v.x; s.y += v.y; s.z += v.z; s.w += v.w;
  }
  const float r = 1.0f/(float)Pc;
  bf16x4 o = { (bf16)(s.x*r), (bf16)(s.y*r), (bf16)(s.z*r), (bf16)(s.w*r) };
  *(bf16x4*)&feat[b*Fc + f0] = o;
}

__global__ void conv_kernel(const float* __restrict__ src, bf16* __restrict__ dst, int n4){
  int i = blockIdx.x*256 + threadIdx.x;
  if (i >= n4) return;
  float4 v = ((const float4*)src)[i];
  bf16x4 o = { (bf16)v.x, (bf16)v.y, (bf16)v.z, (bf16)v.w };
  *(bf16x4*)&dst[i*4] = o;
}

// W_ih (4096,512) -> permuted rows: row' = j*4+g  <-  row g*1024+j ; plain bf16
__global__ void permconv_ih(const float* __restrict__ W, bf16* __restrict__ Wp){
  int i = blockIdx.x*256 + threadIdx.x;
  if (i >= G4c*Ec/4) return;
  int i4 = i*4;
  int rp = i4 >> 9, k = i4 & 511;
  int g = rp & 3, j = rp >> 2;
  float4 v = *(const float4*)&W[(size_t)(g*Hc + j)*Ec + k];
  bf16x4 o = { (bf16)v.x, (bf16)v.y, (bf16)v.z, (bf16)v.w };
  *(bf16x4*)&Wp[i4] = o;
}

// W_hh (4096,1024) -> permuted + split hi/lo
__global__ void permsplit_hh(const float* __restrict__ W, bf16* __restrict__ Whi, bf16* __restrict__ Wlo){
  int i = blockIdx.x*256 + threadIdx.x;
  if (i >= G4c*Hc/4) return;
  int i4 = i*4;
  int rp = i4 >> 10, k = i4 & 1023;
  int g = rp & 3, j = rp >> 2;
  float4 v = *(const float4*)&W[(size_t)(g*Hc + j)*Hc + k];
  bf16 h0=(bf16)v.x, h1=(bf16)v.y, h2=(bf16)v.z, h3=(bf16)v.w;
  bf16x4 hi = { h0, h1, h2, h3 };
  bf16x4 lo = { (bf16)(v.x-(float)h0), (bf16)(v.y-(float)h1), (bf16)(v.z-(float)h2), (bf16)(v.w-(float)h3) };
  *(bf16x4*)&Whi[i4] = hi;
  *(bf16x4*)&Wlo[i4] = lo;
}

__global__ void split_kernel(const float* __restrict__ W, bf16* __restrict__ Whi, bf16* __restrict__ Wlo, int n4){
  int i = blockIdx.x*256 + threadIdx.x;
  if (i >= n4) return;
  float4 v = ((const float4*)W)[i];
  bf16 h0=(bf16)v.x, h1=(bf16)v.y, h2=(bf16)v.z, h3=(bf16)v.w;
  bf16x4 hi = { h0, h1, h2, h3 };
  bf16x4 lo = { (bf16)(v.x-(float)h0), (bf16)(v.y-(float)h1), (bf16)(v.z-(float)h2), (bf16)(v.w-(float)h3) };
  *(bf16x4*)&Whi[i*4] = hi;
  *(bf16x4*)&Wlo[i*4] = lo;
}

__global__ void bcomb_kernel(const float* __restrict__ bih, const float* __restrict__ bhh, float* __restrict__ bc){
  int i = blockIdx.x*256 + threadIdx.x;
  if (i >= G4c) return;
  int g = i & 3, j = i >> 2;
  bc[i] = bih[g*Hc + j] + bhh[g*Hc + j];
}

// embedding gather into X_all rows 128..3967 (row = s*128+b holds x_s = emb_{s-1})
__global__ void gather_kernel(const float* __restrict__ emb, const int* __restrict__ gt, bf16* __restrict__ X){
  int idx = blockIdx.x*256 + threadIdx.x;
  if (idx >= MOUTc*(Ec/4)) return;
  int r = idx >> 7, ei = (idx & 127) * 4;
  int s = (r >> 7) + 1, b = r & 127;
  int tok = gt[b*(TMAXc+1) + (s-1)];
  float4 v = *(const float4*)(emb + (size_t)tok*Ec + ei);
  bf16x4 o = { (bf16)v.x, (bf16)v.y, (bf16)v.z, (bf16)v.w };
  *(bf16x4*)&X[(size_t)(s*Bc + b)*Ec + ei] = o;
}

// valid-row index build: meta[0]=R, meta[1+i]=row id (t*128+b), t-major, padded w/ 0
__global__ void build_ridx(const int* __restrict__ lens, int* __restrict__ meta){
  int i = blockIdx.x*256 + threadIdx.x;
  if (i >= MOUTc) return;
  int t = i >> 7, b = i & 127;
  int S = 0, R = 0;
  for (int bb = 0; bb < 128; ++bb) {
    int l = lens[bb] - 1;
    S += (t < l) ? t : l;
    R += l;
  }
  if (i == 0) meta[0] = R;
  if (i >= R) meta[1 + i] = 0;
  if (t < lens[b] - 1) meta[1 + S + b] = i;
}

// zero the masked output rows (valid rows are written by the FC GEMM)
__global__ void zerofill(const int* __restrict__ lens, float* __restrict__ out){
  int i = blockIdx.x*256 + threadIdx.x;
  if (i >= MOUTc*2500) return;
  int row = i / 2500, c4 = i - row*2500;
  int b = row / TMAXc, t = row - b*TMAXc;
  if (t >= lens[b] - 1) {
    float4 z = {0.f,0.f,0.f,0.f};
    *(float4*)(out + (size_t)row*Vc + c4*4) = z;
  }
}

// ---------------- GEMM A split-K: x0 partials (32 blocks = 4 ntiles x 8 kchunks) ----------
__global__ __launch_bounds__(256, 2) void initA(
  const bf16* __restrict__ feat, const bf16* __restrict__ Wi, float* __restrict__ part)
{
  __shared__ alignas(16) bf16 sA[128*32], sB[128*32];
  int tid = threadIdx.x, lane = tid & 63, w = tid >> 6, wr = w >> 1, wc = w & 1;
  int nt = blockIdx.x & 3, kc = blockIdx.x >> 2;
  int n0 = nt*128;

  f32x4 acc[4][4] = {};
  for (int kt = kc*256; kt < kc*256 + 256; kt += 32) {
    #pragma unroll
    for (int is = 0; is < 2; ++is) {
      int p = tid*16 + is*4096;
      int r = p >> 6, c = (p & 63) >> 1;
      int ldsoff = w*512 + is*2048;
      gll16(feat + (size_t)r*Fc + kt + c, &sA[ldsoff]);
      gll16(Wi + (size_t)(n0 + r)*Fc + kt + c, &sB[ldsoff]);
    }
    __syncthreads();
    int koff = (lane >> 4) * 8;
    bf16x8 ah[4], bh[4];
    #pragma unroll
    for (int mi = 0; mi < 4; ++mi)
      ah[mi] = *(const bf16x8*)&sA[(wr*64 + mi*16 + (lane & 15))*32 + koff];
    #pragma unroll
    for (int ni = 0; ni < 4; ++ni)
      bh[ni] = *(const bf16x8*)&sB[(wc*64 + ni*16 + (lane & 15))*32 + koff];
    #pragma unroll
    for (int mi = 0; mi < 4; ++mi)
      #pragma unroll
      for (int ni = 0; ni < 4; ++ni)
        acc[mi][ni] = MFMA_B16(ah[mi], bh[ni], acc[mi][ni]);
    __syncthreads();
  }
  #pragma unroll
  for (int mi = 0; mi < 4; ++mi)
    #pragma unroll
    for (int ni = 0; ni < 4; ++ni) {
      int lrow = wr*64 + mi*16 + ((lane >> 4) << 2);
      int col = n0 + wc*64 + ni*16 + (lane & 15);
      #pragma unroll
      for (int j = 0; j < 4; ++j)
        part[((size_t)kc*128 + lrow + j)*512 + col] = acc[mi][ni][j];
    }
}

// reduce partials + sigmoid + BN -> Xall rows 0..127
__global__ void initB(const float* __restrict__ part, const float* __restrict__ binit,
                      const float* __restrict__ gam, const float* __restrict__ bet,
                      bf16* __restrict__ Xall)
{
  int i = blockIdx.x*256 + threadIdx.x;
  if (i >= 128*512) return;
  int col = i & 511;
  float v = 0.f;
  #pragma unroll
  for (int kc = 0; kc < 8; ++kc) v += part[(size_t)kc*128*512 + i];
  const float rbn = rsqrtf(1.0f + 1e-5f);
  v = fsigm(v + binit[col]);
  v = gam[col]*(v*rbn) + bet[col];
  Xall[i] = (bf16)v;
}

// ---------------- generic MFMA GEMM (128x128 tile, BK=32, nt-major, XCD swizzle) --------
// C[m,n] = sum_k A[m,k]*B[n,k]  (B is N x K row-major).
// EPI: 1 = Xg (bias), 2 = FC (compacted rows via meta, bias, scatter)
template<int EPI, bool SPLIT, bool XSWZ>
__global__ __launch_bounds__(256, 2) void gemm_kernel(
  const bf16* __restrict__ Ahi, const bf16* __restrict__ Alo,
  const bf16* __restrict__ Bhi, const bf16* __restrict__ Blo,
  int M, int N, int K, int mtiles,
  const float* __restrict__ p0,
  bf16* __restrict__ outb, float* __restrict__ outf, const int* __restrict__ meta)
{
  constexpr int BK = 32;
  __shared__ alignas(16) bf16 sAh[128*BK], sBh[128*BK];
  __shared__ alignas(16) bf16 sAl[SPLIT ? 128*BK : 8], sBl[SPLIT ? 128*BK : 8];

  int tid = threadIdx.x;
  int lane = tid & 63, w = tid >> 6, wr = w >> 1, wc = w & 1;
  int bid = blockIdx.x;
  if constexpr (XSWZ) {
    int nwg = gridDim.x, q = nwg >> 3, r = nwg & 7;
    int x = bid & 7, o = bid >> 3;
    bid = (x < r ? x*(q+1) : r*(q+1) + (x-r)*q) + o;
  }
  int nt = bid / mtiles, mt = bid - nt*mtiles;
  int m0 = mt*128, n0 = nt*128;

  int R = M;
  if constexpr (EPI == 2) {
    R = meta[0];
    if (m0 >= R) return;
  }

  int sr = (tid*16) >> 6;
  int gr0, gr1;
  if constexpr (EPI == 2) { gr0 = meta[1 + m0 + sr]; gr1 = meta[1 + m0 + sr + 64]; }
  else                    { gr0 = m0 + sr;           gr1 = m0 + sr + 64; }

  f32x4 acc[4][4] = {};

  for (int kt = 0; kt < K; kt += BK) {
    #pragma unroll
    for (int is = 0; is < 2; ++is) {
      int p = tid*16 + is*4096;
      int r = p >> 6, c = (p & 63) >> 1;
      int ldsoff = w*512 + is*2048;
      int ga = is ? gr1 : gr0;
      gll16(Ahi + (size_t)ga*K + kt + c, &sAh[ldsoff]);
      int rb = n0 + r; rb = rb < N ? rb : N - 1;
      gll16(Bhi + (size_t)rb*K + kt + c, &sBh[ldsoff]);
      if constexpr (SPLIT) {
        gll16(Alo + (size_t)ga*K + kt + c, &sAl[ldsoff]);
        gll16(Blo + (size_t)rb*K + kt + c, &sBl[ldsoff]);
      }
    }
    __syncthreads();

    int koff = (lane >> 4) * 8;
    bf16x8 ah[4], bh[4], al[SPLIT?4:1], bl[SPLIT?4:1];
    #pragma unroll
    for (int mi = 0; mi < 4; ++mi) {
      int rr = wr*64 + mi*16 + (lane & 15);
      ah[mi] = *(const bf16x8*)&sAh[rr*BK + koff];
      if constexpr (SPLIT) al[mi] = *(const bf16x8*)&sAl[rr*BK + koff];
    }
    #pragma unroll
    for (int ni = 0; ni < 4; ++ni) {
      int rr = wc*64 + ni*16 + (lane & 15);
      bh[ni] = *(const bf16x8*)&sBh[rr*BK + koff];
      if constexpr (SPLIT) bl[ni] = *(const bf16x8*)&sBl[rr*BK + koff];
    }
    #pragma unroll
    for (int mi = 0; mi < 4; ++mi)
      #pragma unroll
      for (int ni = 0; ni < 4; ++ni) {
        acc[mi][ni] = MFMA_B16(ah[mi], bh[ni], acc[mi][ni]);
        if constexpr (SPLIT) {
          acc[mi][ni] = MFMA_B16(ah[mi], bl[ni], acc[mi][ni]);
          acc[mi][ni] = MFMA_B16(al[mi], bh[ni], acc[mi][ni]);
        }
      }
    __syncthreads();
  }

  #pragma unroll
  for (int mi = 0; mi < 4; ++mi) {
    #pragma unroll
    for (int ni = 0; ni < 4; ++ni) {
      int lrow = m0 + wr*64 + mi*16 + ((lane >> 4) << 2);
      int col = n0 + wc*64 + ni*16 + (lane & 15);
      #pragma unroll
      for (int j = 0; j < 4; ++j) {
        int rr = lrow + j;
        float v = acc[mi][ni][j];
        if constexpr (EPI == 1) {
          outb[(size_t)rr*G4c + col] = (bf16)(v + p0[col]);
        } else {
          if (rr < R && col < N) {
            int val = meta[1 + rr];
            int t = val >> 7, b = val & 127;
            outf[(size_t)b*(TMAXc*Vc) + (size_t)t*Vc + col] = v + p0[col];
          }
        }
      }
    }
  }
}

// ---------------- persistent LSTM recurrence (dataflow-flagged) ----------------
// 256 blocks x 256 threads, 1 block/CU. Block (strip 0..127, rh 0..1):
// strip owns pcols [strip*32,+32) (= hcols [strip*8,+8)), rh owns rows [rh*64,+64).
// h_s in 32-slot chain [slot][128][1024]; producer 2B agent write-through stores,
// consumer normal cached loads. NO global barrier: per-(step,rh,Kquarter) counters;
// quarter g covers hcols [g*256,+256) = strips [32g,32g+32). Consumer waits per
// quarter (tid0 bounded poll + raw s_barrier + compiler fence) -> MFMA of quarter 0
// overlaps tail producers of quarters 1..3. rh half exits at Lh = lens[rh*64] steps.

__global__ __launch_bounds__(256, 1) void lstm_persist(
  const bf16* __restrict__ Whi, const bf16* __restrict__ Wlo, // [4096][1024] permuted
  const bf16* __restrict__ Xg,                                 // [31*128][4096]
  bf16* __restrict__ hCh, bf16* __restrict__ hCl,              // chains, slot0 zeroed
  bf16* __restrict__ Hh, bf16* __restrict__ Hl,                // [3840][1024]
  const int* __restrict__ lens,
  int* __restrict__ flg)                                       // [32][2][4] counters
{
  extern __shared__ char sWc[];    // 128 KB: hi at 0, lo at +65536, swizzled
  int tid = threadIdx.x, lane = tid & 63, w = tid >> 6;
  int bid = blockIdx.x;
  int strip = bid >> 1, rh = bid & 1;
  int pc0 = strip * 32;
  int row0 = rh * 64 + w * 16;
  int grp = strip >> 5;            // my K-quarter group

  // ---- fill W slice into LDS (one-time), swizzle byte ^= (p&7)<<4 ----
  for (int ch = tid; ch < 4096; ch += 256) {
    int p = ch >> 7;
    int k = (ch & 127) * 8;
    bf16x8 vh = *(const bf16x8*)&Whi[(size_t)(pc0 + p)*Hc + k];
    bf16x8 vl = *(const bf16x8*)&Wlo[(size_t)(pc0 + p)*Hc + k];
    int be = (p*Hc + k)*2;
    int sw = (p & 7) << 4;
    *(bf16x8*)(sWc + (be ^ sw)) = vh;
    *(bf16x8*)(sWc + ((be + 65536) ^ sw)) = vl;
  }
  __syncthreads();

  int bp = lane & 15;
  int bk = (lane >> 4) << 3;
  int bswz = (bp & 7) << 4;
  int rbase = row0 + ((lane >> 4) << 2);
  int e = lane & 3;

  int Lh = lens[rh * 64];          // max len in this half (sorted desc)
  if (Lh > NSTEP) Lh = NSTEP;

  float creg[2][4] = {};
  float xgv[2][4];
  #pragma unroll
  for (int ni = 0; ni < 2; ++ni)
    #pragma unroll
    for (int j = 0; j < 4; ++j)
      xgv[ni][j] = (float)Xg[(size_t)(rbase + j)*G4c + pc0 + ni*16 + bp];

  #pragma unroll 1
  for (int s = 0; s < Lh; ++s) {
    const bf16* pah = hCh + (size_t)s*Bc*Hc + (size_t)(row0 + bp)*Hc + bk;
    const bf16* pal = hCl + (size_t)s*Bc*Hc + (size_t)(row0 + bp)*Hc + bk;
    bf16* hwh = hCh + (size_t)(s+1)*Bc*Hc;
    bf16* hwl = hCl + (size_t)(s+1)*Bc*Hc;

    f32x4 aHH[2], aHL[2], aLH[2];
    #pragma unroll
    for (int ni = 0; ni < 2; ++ni) {
      #pragma unroll
      for (int j = 0; j < 4; ++j) aHH[ni][j] = xgv[ni][j];
      aHL[ni] = (f32x4){0.f,0.f,0.f,0.f};
      aLH[ni] = (f32x4){0.f,0.f,0.f,0.f};
    }

    // K loop in 4 quarters, each gated by its producer-group counter
    #pragma unroll 1
    for (int g = 0; g < 4; ++g) {
      if (s > 0) {
        if (tid == 0) waitflag(&flg[(s*2 + rh)*4 + g], 32);
        __builtin_amdgcn_s_barrier();   // raw: no vmcnt drain, loads stay in flight
        asm volatile("" ::: "memory");  // compiler fence: no load hoisting above gate
      }
      #pragma unroll
      for (int k8 = 0; k8 < 8; ++k8) {
        int ks = g*8 + k8;
        bf16x8 avh = *(const bf16x8*)(pah + ks*32);
        bf16x8 avl = *(const bf16x8*)(pal + ks*32);
        #pragma unroll
        for (int ni = 0; ni < 2; ++ni) {
          int be = ((ni*16 + bp)*Hc + ks*32 + bk)*2;
          bf16x8 bvh = *(const bf16x8*)(sWc + (be ^ bswz));
          bf16x8 bvl = *(const bf16x8*)(sWc + ((be + 65536) ^ bswz));
          aHH[ni] = MFMA_B16(avh, bvh, aHH[ni]);
          aHL[ni] = MFMA_B16(avh, bvl, aHL[ni]);
          aLH[ni] = MFMA_B16(avl, bvh, aLH[ni]);
        }
      }
    }

    // ---- LSTM epilogue: combine 4 gates across lane-quads ----
    #pragma unroll
    for (int ni = 0; ni < 2; ++ni) {
      int pcol = pc0 + ni*16 + bp;
      int hcol = pcol >> 2;
      #pragma unroll
      for (int j = 0; j < 4; ++j) {
        int rr = rbase + j;
        float v = aHH[ni][j] + aHL[ni][j] + aLH[ni][j];
        float a  = v;
        float b1 = __shfl_xor(v, 1);
        float c2 = __shfl_xor(v, 2);
        float d3 = __shfl_xor(v, 3);
        int m;
        m = e;     float gI = (m==0)?a:(m==1)?b1:(m==2)?c2:d3;
        m = e ^ 1; float gF = (m==0)?a:(m==1)?b1:(m==2)?c2:d3;
        m = e ^ 2; float gG = (m==0)?a:(m==1)?b1:(m==2)?c2:d3;
        m = e ^ 3; float gO = (m==0)?a:(m==1)?b1:(m==2)?c2:d3;

        float co = creg[ni][j];
        float cn = fsigm(gF)*co + fsigm(gI)*ftanh(gG);
        float hn = fsigm(gO)*ftanh(cn);
        creg[ni][j] = cn;
        bf16 hhi = (bf16)hn;
        bf16 hlo = (bf16)(hn - (float)hhi);
        size_t oi = (size_t)rr*Hc + hcol;
        if (e == 1) ast2(&hwh[oi], hhi);
        else if (e == 2) ast2(&hwl[oi], hlo);
        if (s > 0) {
          size_t ho = (size_t)((s-1)*Bc + rr)*Hc + hcol;
          if (e == 0) Hh[ho] = hhi;
          else if (e == 3) Hl[ho] = hlo;
        }
      }
    }

    __syncthreads();                 // drains vmcnt: h stores committed at MALL
    if (tid == 0 && s + 1 < Lh)
      __hip_atomic_fetch_add(&flg[((s+1)*2 + rh)*4 + grp], 1,
                             __ATOMIC_RELAXED, __HIP_MEMORY_SCOPE_AGENT);

    // prefetch next step's Xg (independent of h)
    if (s + 1 < Lh) {
      #pragma unroll
      for (int ni = 0; ni < 2; ++ni)
        #pragma unroll
        for (int j = 0; j < 4; ++j)
          xgv[ni][j] = (float)Xg[(size_t)((s+1)*Bc + rbase + j)*G4c + pc0 + ni*16 + bp];
    }
  }
}

// ---------------- launch ----------------

extern "C" void kernel_launch(void* const* d_in, const int* in_sizes, int n_in,
                              void* d_out, int out_size, void* d_ws, size_t ws_size,
                              hipStream_t stream)
{
  const float* enc   = (const float*)d_in[0];
  const int*   gt    = (const int*)  d_in[1];
  const int*   lens  = (const int*)  d_in[2];
  const float* emb   = (const float*)d_in[3];
  const float* Winit = (const float*)d_in[4];
  const float* binit = (const float*)d_in[5];
  const float* gam   = (const float*)d_in[6];
  const float* bet   = (const float*)d_in[7];
  const float* Wih   = (const float*)d_in[8];
  const float* bih   = (const float*)d_in[9];
  const float* Whh   = (const float*)d_in[10];
  const float* bhh   = (const float*)d_in[11];
  const float* Wfc   = (const float*)d_in[12];
  const float* bfc   = (const float*)d_in[13];
  float* out = (float*)d_out;

  char* ws = (char*)d_ws;
  size_t off = 0;
  auto alloc = [&](size_t bytes) -> char* {
    char* p = ws + off;
    off += (bytes + 255) & ~(size_t)255;
    return p;
  };

  bf16* featB  = (bf16*)alloc((size_t)Bc*Fc*2);
  bf16* WinitB = (bf16*)alloc((size_t)Ec*Fc*2);
  bf16* WihpB  = (bf16*)alloc((size_t)G4c*Ec*2);
  bf16* WhhHi  = (bf16*)alloc((size_t)G4c*Hc*2);
  bf16* WhhLo  = (bf16*)alloc((size_t)G4c*Hc*2);
  bf16* WfcHi  = (bf16*)alloc((size_t)Vc*Hc*2);
  bf16* WfcLo  = (bf16*)alloc((size_t)Vc*Hc*2);
  float* bcomb = (float*)alloc((size_t)G4c*4);
  bf16* Xall   = (bf16*)alloc((size_t)MALLc*Ec*2);
  bf16* Xg     = (bf16*)alloc((size_t)MALLc*G4c*2);
  bf16* hChH   = (bf16*)alloc((size_t)(NSTEP+1)*Bc*Hc*2);  // 32-slot chain
  bf16* hChL   = (bf16*)alloc((size_t)(NSTEP+1)*Bc*Hc*2);
  bf16* HallH  = (bf16*)alloc((size_t)MOUTc*Hc*2);
  bf16* HallL  = (bf16*)alloc((size_t)MOUTc*Hc*2);
  float* part  = (float*)alloc((size_t)8*128*512*4);
  int*  meta   = (int*) alloc((size_t)(1 + MOUTc)*4);
  int*  flg    = (int*) alloc((size_t)256*4);

  if (off > ws_size) return;

  // zero initial state + flags (captured in graph -> re-done every replay)
  hipMemsetAsync(hChH, 0, (size_t)Bc*Hc*2, stream);
  hipMemsetAsync(hChL, 0, (size_t)Bc*Hc*2, stream);
  hipMemsetAsync(flg, 0, (size_t)256*4, stream);

  // prep
  mean_kernel<<<256, 256, 0, stream>>>(enc, featB);
  conv_kernel<<<(Ec*Fc/4 + 255)/256, 256, 0, stream>>>(Winit, WinitB, Ec*Fc/4);
  permconv_ih<<<(G4c*Ec/4 + 255)/256, 256, 0, stream>>>(Wih, WihpB);
  permsplit_hh<<<(G4c*Hc/4 + 255)/256, 256, 0, stream>>>(Whh, WhhHi, WhhLo);
  split_kernel<<<(Vc*Hc/4 + 255)/256, 256, 0, stream>>>(Wfc, WfcHi, WfcLo, Vc*Hc/4);
  bcomb_kernel<<<(G4c + 255)/256, 256, 0, stream>>>(bih, bhh, bcomb);
  gather_kernel<<<(MOUTc*(Ec/4) + 255)/256, 256, 0, stream>>>(emb, gt, Xall);
  build_ridx<<<(MOUTc + 255)/256, 256, 0, stream>>>(lens, meta);
  zerofill<<<(MOUTc*2500 + 255)/256, 256, 0, stream>>>(lens, out);

  // GEMM A (split-K): x0 = sigmoid(feat @ Winit^T + b) * BN -> X_all rows 0..127
  initA<<<32, 256, 0, stream>>>(featB, WinitB, part);
  initB<<<(128*512 + 255)/256, 256, 0, stream>>>(part, binit, gam, bet, Xall);

  // GEMM C: Xg = X_all @ Wihp^T + bcomb   (3968 x 4096, K=512), nt-major + XCD swizzle
  gemm_kernel<1,false,true><<<31*32, 256, 0, stream>>>(
      Xall, nullptr, WihpB, nullptr, MALLc, G4c, Ec, 31,
      bcomb, Xg, nullptr, nullptr);

  // recurrence: one persistent kernel, dataflow-flagged steps
  hipFuncSetAttribute(reinterpret_cast<const void*>(lstm_persist),
                      hipFuncAttributeMaxDynamicSharedMemorySize, 131072);
  lstm_persist<<<NBLK, 256, 131072, stream>>>(
      WhhHi, WhhLo, Xg, hChH, hChL, HallH, HallL, lens, flg);

  // GEMM E: preds = Hall[compacted] @ Wfc^T + b_fc -> scatter to out (split-3 + XCD swizzle)
  gemm_kernel<2,true,true><<<79*30, 256, 0, stream>>>(
      HallH, HallL, WfcHi, WfcLo, MOUTc, Vc, Hc, 30,
      bfc, nullptr, out, meta);
}

// Round 10
// 760.045 us; speedup vs baseline: 1.3493x; 1.0224x over previous
//
#include <hip/hip_runtime.h>
#include <math.h>

typedef __bf16 bf16;
typedef __bf16 bf16x8 __attribute__((ext_vector_type(8)));
typedef __bf16 bf16x4 __attribute__((ext_vector_type(4)));
typedef float f32x4 __attribute__((ext_vector_type(4)));

#define MFMA_B16(a,b,c) __builtin_amdgcn_mfma_f32_16x16x32_bf16((a),(b),(c),0,0,0)

constexpr int TMAXc = 30;
constexpr int Bc = 128, Pc = 196, Fc = 2048, Ec = 512, Hc = 1024, Vc = 10000;
constexpr int G4c = 4 * Hc;          // 4096
constexpr int NSTEP = TMAXc + 1;     // 31
constexpr int MALLc = NSTEP * Bc;    // 3968
constexpr int MOUTc = TMAXc * Bc;    // 3840
constexpr int NBLK = 256;            // persistent kernel grid

__device__ __forceinline__ float fsigm(float x){
  return __fdividef(1.0f, 1.0f + __expf(-x));
}
__device__ __forceinline__ float ftanh(float x){
  return 1.0f - __fdividef(2.0f, __expf(2.0f*x) + 1.0f);
}

__device__ __forceinline__ void gll16(const void* g, void* l){
  __builtin_amdgcn_global_load_lds((const __attribute__((address_space(1))) void*)g,
                                   (__attribute__((address_space(3))) void*)l, 16, 0, 0);
}

// 2B agent-scope write-through store (h goes to MALL; no fence/invalidate needed)
__device__ __forceinline__ void ast2(bf16* p, bf16 v){
  unsigned short b = __builtin_bit_cast(unsigned short, v);
  __hip_atomic_store((unsigned short*)p, b, __ATOMIC_RELAXED, __HIP_MEMORY_SCOPE_AGENT);
}

// bounded spin: escapes after ~1ms (s_memrealtime = 100 MHz const clock).
// Healthy runs resolve in ~us; the bound converts any protocol bug into a
// visible validation failure instead of a GPU hang.
__device__ __forceinline__ void waitflag(int* f, int tgt){
  long long t0 = __builtin_amdgcn_s_memrealtime();
  while (__hip_atomic_load(f, __ATOMIC_RELAXED, __HIP_MEMORY_SCOPE_AGENT) < tgt) {
    __builtin_amdgcn_s_sleep(1);
    if (__builtin_amdgcn_s_memrealtime() - t0 > 100000) break;
  }
}

// ---------------- prep kernels ----------------

__global__ void mean_kernel(const float* __restrict__ enc, bf16* __restrict__ feat){
  int blk = blockIdx.x, b = blk >> 1, half = blk & 1;
  int f0 = half*1024 + threadIdx.x*4;
  const float* p = enc + (size_t)b*Pc*Fc + f0;
  float4 s = {0.f,0.f,0.f,0.f};
  #pragma unroll 4
  for (int q = 0; q < Pc; ++q) {
    float4 v = *(const float4*)(p + (size_t)q*Fc);
    s.x += v.x; s.y += v.y; s.z += v.z; s.w += v.w;
  }
  const float r = 1.0f/(float)Pc;
  bf16x4 o = { (bf16)(s.x*r), (bf16)(s.y*r), (bf16)(s.z*r), (bf16)(s.w*r) };
  *(bf16x4*)&feat[b*Fc + f0] = o;
}

__global__ void conv_kernel(const float* __restrict__ src, bf16* __restrict__ dst, int n4){
  int i = blockIdx.x*256 + threadIdx.x;
  if (i >= n4) return;
  float4 v = ((const float4*)src)[i];
  bf16x4 o = { (bf16)v.x, (bf16)v.y, (bf16)v.z, (bf16)v.w };
  *(bf16x4*)&dst[i*4] = o;
}

__global__ void permconv_ih(const float* __restrict__ W, bf16* __restrict__ Wp){
  int i = blockIdx.x*256 + threadIdx.x;
  if (i >= G4c*Ec/4) return;
  int i4 = i*4;
  int rp = i4 >> 9, k = i4 & 511;
  int g = rp & 3, j = rp >> 2;
  float4 v = *(const float4*)&W[(size_t)(g*Hc + j)*Ec + k];
  bf16x4 o = { (bf16)v.x, (bf16)v.y, (bf16)v.z, (bf16)v.w };
  *(bf16x4*)&Wp[i4] = o;
}

__global__ void permsplit_hh(const float* __restrict__ W, bf16* __restrict__ Whi, bf16* __restrict__ Wlo){
  int i = blockIdx.x*256 + threadIdx.x;
  if (i >= G4c*Hc/4) return;
  int i4 = i*4;
  int rp = i4 >> 10, k = i4 & 1023;
  int g = rp & 3, j = rp >> 2;
  float4 v = *(const float4*)&W[(size_t)(g*Hc + j)*Hc + k];
  bf16 h0=(bf16)v.x, h1=(bf16)v.y, h2=(bf16)v.z, h3=(bf16)v.w;
  bf16x4 hi = { h0, h1, h2, h3 };
  bf16x4 lo = { (bf16)(v.x-(float)h0), (bf16)(v.y-(float)h1), (bf16)(v.z-(float)h2), (bf16)(v.w-(float)h3) };
  *(bf16x4*)&Whi[i4] = hi;
  *(bf16x4*)&Wlo[i4] = lo;
}

__global__ void split_kernel(const float* __restrict__ W, bf16* __restrict__ Whi, bf16* __restrict__ Wlo, int n4){
  int i = blockIdx.x*256 + threadIdx.x;
  if (i >= n4) return;
  float4 v = ((const float4*)W)[i];
  bf16 h0=(bf16)v.x, h1=(bf16)v.y, h2=(bf16)v.z, h3=(bf16)v.w;
  bf16x4 hi = { h0, h1, h2, h3 };
  bf16x4 lo = { (bf16)(v.x-(float)h0), (bf16)(v.y-(float)h1), (bf16)(v.z-(float)h2), (bf16)(v.w-(float)h3) };
  *(bf16x4*)&Whi[i*4] = hi;
  *(bf16x4*)&Wlo[i*4] = lo;
}

__global__ void bcomb_kernel(const float* __restrict__ bih, const float* __restrict__ bhh, float* __restrict__ bc){
  int i = blockIdx.x*256 + threadIdx.x;
  if (i >= G4c) return;
  int g = i & 3, j = i >> 2;
  bc[i] = bih[g*Hc + j] + bhh[g*Hc + j];
}

__global__ void gather_kernel(const float* __restrict__ emb, const int* __restrict__ gt, bf16* __restrict__ X){
  int idx = blockIdx.x*256 + threadIdx.x;
  if (idx >= MOUTc*(Ec/4)) return;
  int r = idx >> 7, ei = (idx & 127) * 4;
  int s = (r >> 7) + 1, b = r & 127;
  int tok = gt[b*(TMAXc+1) + (s-1)];
  float4 v = *(const float4*)(emb + (size_t)tok*Ec + ei);
  bf16x4 o = { (bf16)v.x, (bf16)v.y, (bf16)v.z, (bf16)v.w };
  *(bf16x4*)&X[(size_t)(s*Bc + b)*Ec + ei] = o;
}

__global__ void build_ridx(const int* __restrict__ lens, int* __restrict__ meta){
  int i = blockIdx.x*256 + threadIdx.x;
  if (i >= MOUTc) return;
  int t = i >> 7, b = i & 127;
  int S = 0, R = 0;
  for (int bb = 0; bb < 128; ++bb) {
    int l = lens[bb] - 1;
    S += (t < l) ? t : l;
    R += l;
  }
  if (i == 0) meta[0] = R;
  if (i >= R) meta[1 + i] = 0;
  if (t < lens[b] - 1) meta[1 + S + b] = i;
}

__global__ void zerofill(const int* __restrict__ lens, float* __restrict__ out){
  int i = blockIdx.x*256 + threadIdx.x;
  if (i >= MOUTc*2500) return;
  int row = i / 2500, c4 = i - row*2500;
  int b = row / TMAXc, t = row - b*TMAXc;
  if (t >= lens[b] - 1) {
    float4 z = {0.f,0.f,0.f,0.f};
    *(float4*)(out + (size_t)row*Vc + c4*4) = z;
  }
}

// ---------------- GEMM A split-K: x0 partials (32 blocks = 4 ntiles x 8 kchunks) ----------
__global__ __launch_bounds__(256, 2) void initA(
  const bf16* __restrict__ feat, const bf16* __restrict__ Wi, float* __restrict__ part)
{
  __shared__ alignas(16) bf16 sA[128*32], sB[128*32];
  int tid = threadIdx.x, lane = tid & 63, w = tid >> 6, wr = w >> 1, wc = w & 1;
  int nt = blockIdx.x & 3, kc = blockIdx.x >> 2;
  int n0 = nt*128;

  f32x4 acc[4][4] = {};
  for (int kt = kc*256; kt < kc*256 + 256; kt += 32) {
    #pragma unroll
    for (int is = 0; is < 2; ++is) {
      int p = tid*16 + is*4096;
      int r = p >> 6, c = (p & 63) >> 1;
      int ldsoff = w*512 + is*2048;
      gll16(feat + (size_t)r*Fc + kt + c, &sA[ldsoff]);
      gll16(Wi + (size_t)(n0 + r)*Fc + kt + c, &sB[ldsoff]);
    }
    __syncthreads();
    int koff = (lane >> 4) * 8;
    bf16x8 ah[4], bh[4];
    #pragma unroll
    for (int mi = 0; mi < 4; ++mi)
      ah[mi] = *(const bf16x8*)&sA[(wr*64 + mi*16 + (lane & 15))*32 + koff];
    #pragma unroll
    for (int ni = 0; ni < 4; ++ni)
      bh[ni] = *(const bf16x8*)&sB[(wc*64 + ni*16 + (lane & 15))*32 + koff];
    #pragma unroll
    for (int mi = 0; mi < 4; ++mi)
      #pragma unroll
      for (int ni = 0; ni < 4; ++ni)
        acc[mi][ni] = MFMA_B16(ah[mi], bh[ni], acc[mi][ni]);
    __syncthreads();
  }
  #pragma unroll
  for (int mi = 0; mi < 4; ++mi)
    #pragma unroll
    for (int ni = 0; ni < 4; ++ni) {
      int lrow = wr*64 + mi*16 + ((lane >> 4) << 2);
      int col = n0 + wc*64 + ni*16 + (lane & 15);
      #pragma unroll
      for (int j = 0; j < 4; ++j)
        part[((size_t)kc*128 + lrow + j)*512 + col] = acc[mi][ni][j];
    }
}

__global__ void initB(const float* __restrict__ part, const float* __restrict__ binit,
                      const float* __restrict__ gam, const float* __restrict__ bet,
                      bf16* __restrict__ Xall)
{
  int i = blockIdx.x*256 + threadIdx.x;
  if (i >= 128*512) return;
  int col = i & 511;
  float v = 0.f;
  #pragma unroll
  for (int kc = 0; kc < 8; ++kc) v += part[(size_t)kc*128*512 + i];
  const float rbn = rsqrtf(1.0f + 1e-5f);
  v = fsigm(v + binit[col]);
  v = gam[col]*(v*rbn) + bet[col];
  Xall[i] = (bf16)v;
}

// ---------------- generic MFMA GEMM (128x128 tile, BK=32, nt-major, XCD swizzle) --------
template<int EPI, bool SPLIT, bool XSWZ>
__global__ __launch_bounds__(256, 2) void gemm_kernel(
  const bf16* __restrict__ Ahi, const bf16* __restrict__ Alo,
  const bf16* __restrict__ Bhi, const bf16* __restrict__ Blo,
  int M, int N, int K, int mtiles,
  const float* __restrict__ p0,
  bf16* __restrict__ outb, float* __restrict__ outf, const int* __restrict__ meta)
{
  constexpr int BK = 32;
  __shared__ alignas(16) bf16 sAh[128*BK], sBh[128*BK];
  __shared__ alignas(16) bf16 sAl[SPLIT ? 128*BK : 8], sBl[SPLIT ? 128*BK : 8];

  int tid = threadIdx.x;
  int lane = tid & 63, w = tid >> 6, wr = w >> 1, wc = w & 1;
  int bid = blockIdx.x;
  if constexpr (XSWZ) {
    int nwg = gridDim.x, q = nwg >> 3, r = nwg & 7;
    int x = bid & 7, o = bid >> 3;
    bid = (x < r ? x*(q+1) : r*(q+1) + (x-r)*q) + o;
  }
  int nt = bid / mtiles, mt = bid - nt*mtiles;
  int m0 = mt*128, n0 = nt*128;

  int R = M;
  if constexpr (EPI == 2) {
    R = meta[0];
    if (m0 >= R) return;
  }

  int sr = (tid*16) >> 6;
  int gr0, gr1;
  if constexpr (EPI == 2) { gr0 = meta[1 + m0 + sr]; gr1 = meta[1 + m0 + sr + 64]; }
  else                    { gr0 = m0 + sr;           gr1 = m0 + sr + 64; }

  f32x4 acc[4][4] = {};

  for (int kt = 0; kt < K; kt += BK) {
    #pragma unroll
    for (int is = 0; is < 2; ++is) {
      int p = tid*16 + is*4096;
      int r = p >> 6, c = (p & 63) >> 1;
      int ldsoff = w*512 + is*2048;
      int ga = is ? gr1 : gr0;
      gll16(Ahi + (size_t)ga*K + kt + c, &sAh[ldsoff]);
      int rb = n0 + r; rb = rb < N ? rb : N - 1;
      gll16(Bhi + (size_t)rb*K + kt + c, &sBh[ldsoff]);
      if constexpr (SPLIT) {
        gll16(Alo + (size_t)ga*K + kt + c, &sAl[ldsoff]);
        gll16(Blo + (size_t)rb*K + kt + c, &sBl[ldsoff]);
      }
    }
    __syncthreads();

    int koff = (lane >> 4) * 8;
    bf16x8 ah[4], bh[4], al[SPLIT?4:1], bl[SPLIT?4:1];
    #pragma unroll
    for (int mi = 0; mi < 4; ++mi) {
      int rr = wr*64 + mi*16 + (lane & 15);
      ah[mi] = *(const bf16x8*)&sAh[rr*BK + koff];
      if constexpr (SPLIT) al[mi] = *(const bf16x8*)&sAl[rr*BK + koff];
    }
    #pragma unroll
    for (int ni = 0; ni < 4; ++ni) {
      int rr = wc*64 + ni*16 + (lane & 15);
      bh[ni] = *(const bf16x8*)&sBh[rr*BK + koff];
      if constexpr (SPLIT) bl[ni] = *(const bf16x8*)&sBl[rr*BK + koff];
    }
    #pragma unroll
    for (int mi = 0; mi < 4; ++mi)
      #pragma unroll
      for (int ni = 0; ni < 4; ++ni) {
        acc[mi][ni] = MFMA_B16(ah[mi], bh[ni], acc[mi][ni]);
        if constexpr (SPLIT) {
          acc[mi][ni] = MFMA_B16(ah[mi], bl[ni], acc[mi][ni]);
          acc[mi][ni] = MFMA_B16(al[mi], bh[ni], acc[mi][ni]);
        }
      }
    __syncthreads();
  }

  #pragma unroll
  for (int mi = 0; mi < 4; ++mi) {
    #pragma unroll
    for (int ni = 0; ni < 4; ++ni) {
      int lrow = m0 + wr*64 + mi*16 + ((lane >> 4) << 2);
      int col = n0 + wc*64 + ni*16 + (lane & 15);
      #pragma unroll
      for (int j = 0; j < 4; ++j) {
        int rr = lrow + j;
        float v = acc[mi][ni][j];
        if constexpr (EPI == 1) {
          outb[(size_t)rr*G4c + col] = (bf16)(v + p0[col]);
        } else {
          if (rr < R && col < N) {
            int val = meta[1 + rr];
            int t = val >> 7, b = val & 127;
            outf[(size_t)b*(TMAXc*Vc) + (size_t)t*Vc + col] = v + p0[col];
          }
        }
      }
    }
  }
}

// ---------------- persistent LSTM recurrence (dataflow + pipelined K-loop) --------------
// 256 blocks x 256 threads, 1 block/CU. Block (strip 0..127, rh 0..1).
// K-loop register-pipelined 2 quarters deep (2x 64-VGPR buffers) so gate polls hide
// load latency and loads hide MFMA; Hall stores + Xg prefetch after the flag signal -
// only chain stores drain on the signaling path.

__global__ __launch_bounds__(256, 1) void lstm_persist(
  const bf16* __restrict__ Whi, const bf16* __restrict__ Wlo,
  const bf16* __restrict__ Xg,
  bf16* __restrict__ hCh, bf16* __restrict__ hCl,
  bf16* __restrict__ Hh, bf16* __restrict__ Hl,
  const int* __restrict__ lens,
  int* __restrict__ flg)
{
  extern __shared__ char sWc[];    // 128 KB: hi at 0, lo at +65536, swizzled
  int tid = threadIdx.x, lane = tid & 63, w = tid >> 6;
  int bid = blockIdx.x;
  int strip = bid >> 1, rh = bid & 1;
  int pc0 = strip * 32;
  int row0 = rh * 64 + w * 16;
  int grp = strip >> 5;

  for (int ch = tid; ch < 4096; ch += 256) {
    int p = ch >> 7;
    int k = (ch & 127) * 8;
    bf16x8 vh = *(const bf16x8*)&Whi[(size_t)(pc0 + p)*Hc + k];
    bf16x8 vl = *(const bf16x8*)&Wlo[(size_t)(pc0 + p)*Hc + k];
    int be = (p*Hc + k)*2;
    int sw = (p & 7) << 4;
    *(bf16x8*)(sWc + (be ^ sw)) = vh;
    *(bf16x8*)(sWc + ((be + 65536) ^ sw)) = vl;
  }
  __syncthreads();

  int bp = lane & 15;
  int bk = (lane >> 4) << 3;
  int bswz = (bp & 7) << 4;
  int rbase = row0 + ((lane >> 4) << 2);
  int e = lane & 3;

  int Lh = lens[rh * 64];
  if (Lh > NSTEP) Lh = NSTEP;

  float creg[2][4] = {};
  float xgv[2][4];
  #pragma unroll
  for (int ni = 0; ni < 2; ++ni)
    #pragma unroll
    for (int j = 0; j < 4; ++j)
      xgv[ni][j] = (float)Xg[(size_t)(rbase + j)*G4c + pc0 + ni*16 + bp];

#define GATEQ(g) do { if (s > 0) { \
    if (tid == 0) waitflag(&flg[(s*2 + rh)*4 + (g)], 32); \
    __builtin_amdgcn_s_barrier(); \
    asm volatile("" ::: "memory"); } } while (0)

#define LOADQ(qh, ql, g) do { \
    _Pragma("unroll") \
    for (int i = 0; i < 8; ++i) { \
      qh[i] = *(const bf16x8*)(pah + ((g)*8 + i)*32); \
      ql[i] = *(const bf16x8*)(pal + ((g)*8 + i)*32); \
    } \
    asm volatile("" ::: "memory"); } while (0)

#define MFMAQ(qh, ql, g) do { \
    _Pragma("unroll") \
    for (int i = 0; i < 8; ++i) { \
      int ks = (g)*8 + i; \
      _Pragma("unroll") \
      for (int ni = 0; ni < 2; ++ni) { \
        int be = ((ni*16 + bp)*Hc + ks*32 + bk)*2; \
        bf16x8 bvh = *(const bf16x8*)(sWc + (be ^ bswz)); \
        bf16x8 bvl = *(const bf16x8*)(sWc + ((be + 65536) ^ bswz)); \
        aHH[ni] = MFMA_B16(qh[i], bvh, aHH[ni]); \
        aHL[ni] = MFMA_B16(qh[i], bvl, aHL[ni]); \
        aLH[ni] = MFMA_B16(ql[i], bvh, aLH[ni]); \
      } \
    } } while (0)

  #pragma unroll 1
  for (int s = 0; s < Lh; ++s) {
    const bf16* pah = hCh + (size_t)s*Bc*Hc + (size_t)(row0 + bp)*Hc + bk;
    const bf16* pal = hCl + (size_t)s*Bc*Hc + (size_t)(row0 + bp)*Hc + bk;
    bf16* hwh = hCh + (size_t)(s+1)*Bc*Hc;
    bf16* hwl = hCl + (size_t)(s+1)*Bc*Hc;

    f32x4 aHH[2], aHL[2], aLH[2];
    #pragma unroll
    for (int ni = 0; ni < 2; ++ni) {
      #pragma unroll
      for (int j = 0; j < 4; ++j) aHH[ni][j] = xgv[ni][j];
      aHL[ni] = (f32x4){0.f,0.f,0.f,0.f};
      aLH[ni] = (f32x4){0.f,0.f,0.f,0.f};
    }

    bf16x8 qh0[8], ql0[8], qh1[8], ql1[8];

    GATEQ(0); LOADQ(qh0, ql0, 0);
    GATEQ(1); LOADQ(qh1, ql1, 1);
    MFMAQ(qh0, ql0, 0);
    GATEQ(2); LOADQ(qh0, ql0, 2);
    MFMAQ(qh1, ql1, 1);
    GATEQ(3); LOADQ(qh1, ql1, 3);
    MFMAQ(qh0, ql0, 2);
    MFMAQ(qh1, ql1, 3);

    // ---- LSTM epilogue: gates -> h; chain stores only (signaling path) ----
    float hnv[2][4];
    #pragma unroll
    for (int ni = 0; ni < 2; ++ni) {
      int pcol = pc0 + ni*16 + bp;
      int hcol = pcol >> 2;
      #pragma unroll
      for (int j = 0; j < 4; ++j) {
        int rr = rbase + j;
        float v = aHH[ni][j] + aHL[ni][j] + aLH[ni][j];
        float a  = v;
        float b1 = __shfl_xor(v, 1);
        float c2 = __shfl_xor(v, 2);
        float d3 = __shfl_xor(v, 3);
        int m;
        m = e;     float gI = (m==0)?a:(m==1)?b1:(m==2)?c2:d3;
        m = e ^ 1; float gF = (m==0)?a:(m==1)?b1:(m==2)?c2:d3;
        m = e ^ 2; float gG = (m==0)?a:(m==1)?b1:(m==2)?c2:d3;
        m = e ^ 3; float gO = (m==0)?a:(m==1)?b1:(m==2)?c2:d3;

        float co = creg[ni][j];
        float cn = fsigm(gF)*co + fsigm(gI)*ftanh(gG);
        float hn = fsigm(gO)*ftanh(cn);
        creg[ni][j] = cn;
        hnv[ni][j] = hn;
        bf16 hhi = (bf16)hn;
        size_t oi = (size_t)rr*Hc + hcol;
        if (e == 1) ast2(&hwh[oi], hhi);
        else if (e == 2) ast2(&hwl[oi], (bf16)(hn - (float)hhi));
      }
    }

    __syncthreads();                 // drains chain stores (vmcnt 0) for whole block
    if (tid == 0 && s + 1 < Lh)
      __hip_atomic_fetch_add(&flg[((s+1)*2 + rh)*4 + grp], 1,
                             __ATOMIC_RELAXED, __HIP_MEMORY_SCOPE_AGENT);

    // ---- off-path work: Hall stores + Xg prefetch (drain under next gate) ----
    if (s > 0) {
      #pragma unroll
      for (int ni = 0; ni < 2; ++ni) {
        int hcol = (pc0 + ni*16 + bp) >> 2;
        #pragma unroll
        for (int j = 0; j < 4; ++j) {
          float hn = hnv[ni][j];
          bf16 hhi = (bf16)hn;
          size_t ho = (size_t)((s-1)*Bc + rbase + j)*Hc + hcol;
          if (e == 0) Hh[ho] = hhi;
          else if (e == 3) Hl[ho] = (bf16)(hn - (float)hhi);
        }
      }
    }
    if (s + 1 < Lh) {
      #pragma unroll
      for (int ni = 0; ni < 2; ++ni)
        #pragma unroll
        for (int j = 0; j < 4; ++j)
          xgv[ni][j] = (float)Xg[(size_t)((s+1)*Bc + rbase + j)*G4c + pc0 + ni*16 + bp];
    }
  }
#undef GATEQ
#undef LOADQ
#undef MFMAQ
}

// ---------------- launch ----------------

extern "C" void kernel_launch(void* const* d_in, const int* in_sizes, int n_in,
                              void* d_out, int out_size, void* d_ws, size_t ws_size,
                              hipStream_t stream)
{
  const float* enc   = (const float*)d_in[0];
  const int*   gt    = (const int*)  d_in[1];
  const int*   lens  = (const int*)  d_in[2];
  const float* emb   = (const float*)d_in[3];
  const float* Winit = (const float*)d_in[4];
  const float* binit = (const float*)d_in[5];
  const float* gam   = (const float*)d_in[6];
  const float* bet   = (const float*)d_in[7];
  const float* Wih   = (const float*)d_in[8];
  const float* bih   = (const float*)d_in[9];
  const float* Whh   = (const float*)d_in[10];
  const float* bhh   = (const float*)d_in[11];
  const float* Wfc   = (const float*)d_in[12];
  const float* bfc   = (const float*)d_in[13];
  float* out = (float*)d_out;

  char* ws = (char*)d_ws;
  size_t off = 0;
  auto alloc = [&](size_t bytes) -> char* {
    char* p = ws + off;
    off += (bytes + 255) & ~(size_t)255;
    return p;
  };

  bf16* featB  = (bf16*)alloc((size_t)Bc*Fc*2);
  bf16* WinitB = (bf16*)alloc((size_t)Ec*Fc*2);
  bf16* WihpB  = (bf16*)alloc((size_t)G4c*Ec*2);
  bf16* WhhHi  = (bf16*)alloc((size_t)G4c*Hc*2);
  bf16* WhhLo  = (bf16*)alloc((size_t)G4c*Hc*2);
  bf16* WfcHi  = (bf16*)alloc((size_t)Vc*Hc*2);
  bf16* WfcLo  = (bf16*)alloc((size_t)Vc*Hc*2);
  float* bcomb = (float*)alloc((size_t)G4c*4);
  bf16* Xall   = (bf16*)alloc((size_t)MALLc*Ec*2);
  bf16* Xg     = (bf16*)alloc((size_t)MALLc*G4c*2);
  bf16* hChH   = (bf16*)alloc((size_t)(NSTEP+1)*Bc*Hc*2);
  bf16* hChL   = (bf16*)alloc((size_t)(NSTEP+1)*Bc*Hc*2);
  bf16* HallH  = (bf16*)alloc((size_t)MOUTc*Hc*2);
  bf16* HallL  = (bf16*)alloc((size_t)MOUTc*Hc*2);
  float* part  = (float*)alloc((size_t)8*128*512*4);
  int*  meta   = (int*) alloc((size_t)(1 + MOUTc)*4);
  int*  flg    = (int*) alloc((size_t)256*4);

  if (off > ws_size) return;

  hipMemsetAsync(hChH, 0, (size_t)Bc*Hc*2, stream);
  hipMemsetAsync(hChL, 0, (size_t)Bc*Hc*2, stream);
  hipMemsetAsync(flg, 0, (size_t)256*4, stream);

  mean_kernel<<<256, 256, 0, stream>>>(enc, featB);
  conv_kernel<<<(Ec*Fc/4 + 255)/256, 256, 0, stream>>>(Winit, WinitB, Ec*Fc/4);
  permconv_ih<<<(G4c*Ec/4 + 255)/256, 256, 0, stream>>>(Wih, WihpB);
  permsplit_hh<<<(G4c*Hc/4 + 255)/256, 256, 0, stream>>>(Whh, WhhHi, WhhLo);
  split_kernel<<<(Vc*Hc/4 + 255)/256, 256, 0, stream>>>(Wfc, WfcHi, WfcLo, Vc*Hc/4);
  bcomb_kernel<<<(G4c + 255)/256, 256, 0, stream>>>(bih, bhh, bcomb);
  gather_kernel<<<(MOUTc*(Ec/4) + 255)/256, 256, 0, stream>>>(emb, gt, Xall);
  build_ridx<<<(MOUTc + 255)/256, 256, 0, stream>>>(lens, meta);
  zerofill<<<(MOUTc*2500 + 255)/256, 256, 0, stream>>>(lens, out);

  initA<<<32, 256, 0, stream>>>(featB, WinitB, part);
  initB<<<(128*512 + 255)/256, 256, 0, stream>>>(part, binit, gam, bet, Xall);

  gemm_kernel<1,false,true><<<31*32, 256, 0, stream>>>(
      Xall, nullptr, WihpB, nullptr, MALLc, G4c, Ec, 31,
      bcomb, Xg, nullptr, nullptr);

  hipFuncSetAttribute(reinterpret_cast<const void*>(lstm_persist),
                      hipFuncAttributeMaxDynamicSharedMemorySize, 131072);
  lstm_persist<<<NBLK, 256, 131072, stream>>>(
      WhhHi, WhhLo, Xg, hChH, hChL, HallH, HallL, lens, flg);

  gemm_kernel<2,true,true><<<79*30, 256, 0, stream>>>(
      HallH, HallL, WfcHi, WfcLo, MOUTc, Vc, Hc, 30,
      bfc, nullptr, out, meta);
}

// Round 11
// 739.791 us; speedup vs baseline: 1.3862x; 1.0274x over previous
//
#include <hip/hip_runtime.h>
#include <math.h>

typedef __bf16 bf16;
typedef __bf16 bf16x8 __attribute__((ext_vector_type(8)));
typedef __bf16 bf16x4 __attribute__((ext_vector_type(4)));
typedef float f32x4 __attribute__((ext_vector_type(4)));

#define MFMA_B16(a,b,c) __builtin_amdgcn_mfma_f32_16x16x32_bf16((a),(b),(c),0,0,0)

constexpr int TMAXc = 30;
constexpr int Bc = 128, Pc = 196, Fc = 2048, Ec = 512, Hc = 1024, Vc = 10000;
constexpr int G4c = 4 * Hc;          // 4096
constexpr int NSTEP = TMAXc + 1;     // 31
constexpr int MALLc = NSTEP * Bc;    // 3968
constexpr int MOUTc = TMAXc * Bc;    // 3840
constexpr int NBLK = 256;            // persistent kernel grid

__device__ __forceinline__ float fsigm(float x){
  return __fdividef(1.0f, 1.0f + __expf(-x));
}
__device__ __forceinline__ float ftanh(float x){
  return 1.0f - __fdividef(2.0f, __expf(2.0f*x) + 1.0f);
}

__device__ __forceinline__ void gll16(const void* g, void* l){
  __builtin_amdgcn_global_load_lds((const __attribute__((address_space(1))) void*)g,
                                   (__attribute__((address_space(3))) void*)l, 16, 0, 0);
}

// 16B write-through store (bypasses L1/L2, lands at coherence point / MALL)
__device__ __forceinline__ void wt16(bf16* p, bf16x8 v){
  asm volatile("global_store_dwordx4 %0, %1, off sc0 sc1" :: "v"(p), "v"(v) : "memory");
}

__device__ __forceinline__ int aldf(int* f){
  return __hip_atomic_load(f, __ATOMIC_RELAXED, __HIP_MEMORY_SCOPE_AGENT);
}

// bounded spin: escapes after ~1ms (s_memrealtime = 100 MHz const clock)
__device__ __forceinline__ void waitflag(int* f, int tgt){
  long long t0 = __builtin_amdgcn_s_memrealtime();
  while (aldf(f) < tgt) {
    __builtin_amdgcn_s_sleep(1);
    if (__builtin_amdgcn_s_memrealtime() - t0 > 100000) break;
  }
}

// poll gate0 while snapshotting gates 1-3 in the same round trip
__device__ __forceinline__ void waitflags4(int* F, int& f1, int& f2, int& f3){
  long long t0 = __builtin_amdgcn_s_memrealtime();
  for (;;) {
    int f0 = aldf(F + 0);
    f1 = aldf(F + 1);
    f2 = aldf(F + 2);
    f3 = aldf(F + 3);
    if (f0 >= 32) break;
    __builtin_amdgcn_s_sleep(1);
    if (__builtin_amdgcn_s_memrealtime() - t0 > 100000) break;
  }
}

// ---------------- prep kernels ----------------

__global__ void mean_kernel(const float* __restrict__ enc, bf16* __restrict__ feat){
  int blk = blockIdx.x, b = blk >> 1, half = blk & 1;
  int f0 = half*1024 + threadIdx.x*4;
  const float* p = enc + (size_t)b*Pc*Fc + f0;
  float4 s = {0.f,0.f,0.f,0.f};
  #pragma unroll 4
  for (int q = 0; q < Pc; ++q) {
    float4 v = *(const float4*)(p + (size_t)q*Fc);
    s.x += v.x; s.y += v.y; s.z += v.z; s.w += v.w;
  }
  const float r = 1.0f/(float)Pc;
  bf16x4 o = { (bf16)(s.x*r), (bf16)(s.y*r), (bf16)(s.z*r), (bf16)(s.w*r) };
  *(bf16x4*)&feat[b*Fc + f0] = o;
}

__global__ void conv_kernel(const float* __restrict__ src, bf16* __restrict__ dst, int n4){
  int i = blockIdx.x*256 + threadIdx.x;
  if (i >= n4) return;
  float4 v = ((const float4*)src)[i];
  bf16x4 o = { (bf16)v.x, (bf16)v.y, (bf16)v.z, (bf16)v.w };
  *(bf16x4*)&dst[i*4] = o;
}

__global__ void permconv_ih(const float* __restrict__ W, bf16* __restrict__ Wp){
  int i = blockIdx.x*256 + threadIdx.x;
  if (i >= G4c*Ec/4) return;
  int i4 = i*4;
  int rp = i4 >> 9, k = i4 & 511;
  int g = rp & 3, j = rp >> 2;
  float4 v = *(const float4*)&W[(size_t)(g*Hc + j)*Ec + k];
  bf16x4 o = { (bf16)v.x, (bf16)v.y, (bf16)v.z, (bf16)v.w };
  *(bf16x4*)&Wp[i4] = o;
}

__global__ void permsplit_hh(const float* __restrict__ W, bf16* __restrict__ Whi, bf16* __restrict__ Wlo){
  int i = blockIdx.x*256 + threadIdx.x;
  if (i >= G4c*Hc/4) return;
  int i4 = i*4;
  int rp = i4 >> 10, k = i4 & 1023;
  int g = rp & 3, j = rp >> 2;
  float4 v = *(const float4*)&W[(size_t)(g*Hc + j)*Hc + k];
  bf16 h0=(bf16)v.x, h1=(bf16)v.y, h2=(bf16)v.z, h3=(bf16)v.w;
  bf16x4 hi = { h0, h1, h2, h3 };
  bf16x4 lo = { (bf16)(v.x-(float)h0), (bf16)(v.y-(float)h1), (bf16)(v.z-(float)h2), (bf16)(v.w-(float)h3) };
  *(bf16x4*)&Whi[i4] = hi;
  *(bf16x4*)&Wlo[i4] = lo;
}

__global__ void split_kernel(const float* __restrict__ W, bf16* __restrict__ Whi, bf16* __restrict__ Wlo, int n4){
  int i = blockIdx.x*256 + threadIdx.x;
  if (i >= n4) return;
  float4 v = ((const float4*)W)[i];
  bf16 h0=(bf16)v.x, h1=(bf16)v.y, h2=(bf16)v.z, h3=(bf16)v.w;
  bf16x4 hi = { h0, h1, h2, h3 };
  bf16x4 lo = { (bf16)(v.x-(float)h0), (bf16)(v.y-(float)h1), (bf16)(v.z-(float)h2), (bf16)(v.w-(float)h3) };
  *(bf16x4*)&Whi[i*4] = hi;
  *(bf16x4*)&Wlo[i*4] = lo;
}

__global__ void bcomb_kernel(const float* __restrict__ bih, const float* __restrict__ bhh, float* __restrict__ bc){
  int i = blockIdx.x*256 + threadIdx.x;
  if (i >= G4c) return;
  int g = i & 3, j = i >> 2;
  bc[i] = bih[g*Hc + j] + bhh[g*Hc + j];
}

__global__ void gather_kernel(const float* __restrict__ emb, const int* __restrict__ gt, bf16* __restrict__ X){
  int idx = blockIdx.x*256 + threadIdx.x;
  if (idx >= MOUTc*(Ec/4)) return;
  int r = idx >> 7, ei = (idx & 127) * 4;
  int s = (r >> 7) + 1, b = r & 127;
  int tok = gt[b*(TMAXc+1) + (s-1)];
  float4 v = *(const float4*)(emb + (size_t)tok*Ec + ei);
  bf16x4 o = { (bf16)v.x, (bf16)v.y, (bf16)v.z, (bf16)v.w };
  *(bf16x4*)&X[(size_t)(s*Bc + b)*Ec + ei] = o;
}

__global__ void build_ridx(const int* __restrict__ lens, int* __restrict__ meta){
  int i = blockIdx.x*256 + threadIdx.x;
  if (i >= MOUTc) return;
  int t = i >> 7, b = i & 127;
  int S = 0, R = 0;
  for (int bb = 0; bb < 128; ++bb) {
    int l = lens[bb] - 1;
    S += (t < l) ? t : l;
    R += l;
  }
  if (i == 0) meta[0] = R;
  if (i >= R) meta[1 + i] = 0;
  if (t < lens[b] - 1) meta[1 + S + b] = i;
}

__global__ void zerofill(const int* __restrict__ lens, float* __restrict__ out){
  int i = blockIdx.x*256 + threadIdx.x;
  if (i >= MOUTc*2500) return;
  int row = i / 2500, c4 = i - row*2500;
  int b = row / TMAXc, t = row - b*TMAXc;
  if (t >= lens[b] - 1) {
    float4 z = {0.f,0.f,0.f,0.f};
    *(float4*)(out + (size_t)row*Vc + c4*4) = z;
  }
}

// ---------------- GEMM A split-K: x0 partials (32 blocks = 4 ntiles x 8 kchunks) ----------
__global__ __launch_bounds__(256, 2) void initA(
  const bf16* __restrict__ feat, const bf16* __restrict__ Wi, float* __restrict__ part)
{
  __shared__ alignas(16) bf16 sA[128*32], sB[128*32];
  int tid = threadIdx.x, lane = tid & 63, w = tid >> 6, wr = w >> 1, wc = w & 1;
  int nt = blockIdx.x & 3, kc = blockIdx.x >> 2;
  int n0 = nt*128;

  f32x4 acc[4][4] = {};
  for (int kt = kc*256; kt < kc*256 + 256; kt += 32) {
    #pragma unroll
    for (int is = 0; is < 2; ++is) {
      int p = tid*16 + is*4096;
      int r = p >> 6, c = (p & 63) >> 1;
      int ldsoff = w*512 + is*2048;
      gll16(feat + (size_t)r*Fc + kt + c, &sA[ldsoff]);
      gll16(Wi + (size_t)(n0 + r)*Fc + kt + c, &sB[ldsoff]);
    }
    __syncthreads();
    int koff = (lane >> 4) * 8;
    bf16x8 ah[4], bh[4];
    #pragma unroll
    for (int mi = 0; mi < 4; ++mi)
      ah[mi] = *(const bf16x8*)&sA[(wr*64 + mi*16 + (lane & 15))*32 + koff];
    #pragma unroll
    for (int ni = 0; ni < 4; ++ni)
      bh[ni] = *(const bf16x8*)&sB[(wc*64 + ni*16 + (lane & 15))*32 + koff];
    #pragma unroll
    for (int mi = 0; mi < 4; ++mi)
      #pragma unroll
      for (int ni = 0; ni < 4; ++ni)
        acc[mi][ni] = MFMA_B16(ah[mi], bh[ni], acc[mi][ni]);
    __syncthreads();
  }
  #pragma unroll
  for (int mi = 0; mi < 4; ++mi)
    #pragma unroll
    for (int ni = 0; ni < 4; ++ni) {
      int lrow = wr*64 + mi*16 + ((lane >> 4) << 2);
      int col = n0 + wc*64 + ni*16 + (lane & 15);
      #pragma unroll
      for (int j = 0; j < 4; ++j)
        part[((size_t)kc*128 + lrow + j)*512 + col] = acc[mi][ni][j];
    }
}

__global__ void initB(const float* __restrict__ part, const float* __restrict__ binit,
                      const float* __restrict__ gam, const float* __restrict__ bet,
                      bf16* __restrict__ Xall)
{
  int i = blockIdx.x*256 + threadIdx.x;
  if (i >= 128*512) return;
  int col = i & 511;
  float v = 0.f;
  #pragma unroll
  for (int kc = 0; kc < 8; ++kc) v += part[(size_t)kc*128*512 + i];
  const float rbn = rsqrtf(1.0f + 1e-5f);
  v = fsigm(v + binit[col]);
  v = gam[col]*(v*rbn) + bet[col];
  Xall[i] = (bf16)v;
}

// ---------------- generic MFMA GEMM (128x128 tile, BK=32, nt-major, XCD swizzle) --------
template<int EPI, bool SPLIT, bool XSWZ>
__global__ __launch_bounds__(256, 2) void gemm_kernel(
  const bf16* __restrict__ Ahi, const bf16* __restrict__ Alo,
  const bf16* __restrict__ Bhi, const bf16* __restrict__ Blo,
  int M, int N, int K, int mtiles,
  const float* __restrict__ p0,
  bf16* __restrict__ outb, float* __restrict__ outf, const int* __restrict__ meta)
{
  constexpr int BK = 32;
  __shared__ alignas(16) bf16 sAh[128*BK], sBh[128*BK];
  __shared__ alignas(16) bf16 sAl[SPLIT ? 128*BK : 8], sBl[SPLIT ? 128*BK : 8];

  int tid = threadIdx.x;
  int lane = tid & 63, w = tid >> 6, wr = w >> 1, wc = w & 1;
  int bid = blockIdx.x;
  if constexpr (XSWZ) {
    int nwg = gridDim.x, q = nwg >> 3, r = nwg & 7;
    int x = bid & 7, o = bid >> 3;
    bid = (x < r ? x*(q+1) : r*(q+1) + (x-r)*q) + o;
  }
  int nt = bid / mtiles, mt = bid - nt*mtiles;
  int m0 = mt*128, n0 = nt*128;

  int R = M;
  if constexpr (EPI == 2) {
    R = meta[0];
    if (m0 >= R) return;
  }

  int sr = (tid*16) >> 6;
  int gr0, gr1;
  if constexpr (EPI == 2) { gr0 = meta[1 + m0 + sr]; gr1 = meta[1 + m0 + sr + 64]; }
  else                    { gr0 = m0 + sr;           gr1 = m0 + sr + 64; }

  f32x4 acc[4][4] = {};

  for (int kt = 0; kt < K; kt += BK) {
    #pragma unroll
    for (int is = 0; is < 2; ++is) {
      int p = tid*16 + is*4096;
      int r = p >> 6, c = (p & 63) >> 1;
      int ldsoff = w*512 + is*2048;
      int ga = is ? gr1 : gr0;
      gll16(Ahi + (size_t)ga*K + kt + c, &sAh[ldsoff]);
      int rb = n0 + r; rb = rb < N ? rb : N - 1;
      gll16(Bhi + (size_t)rb*K + kt + c, &sBh[ldsoff]);
      if constexpr (SPLIT) {
        gll16(Alo + (size_t)ga*K + kt + c, &sAl[ldsoff]);
        gll16(Blo + (size_t)rb*K + kt + c, &sBl[ldsoff]);
      }
    }
    __syncthreads();

    int koff = (lane >> 4) * 8;
    bf16x8 ah[4], bh[4], al[SPLIT?4:1], bl[SPLIT?4:1];
    #pragma unroll
    for (int mi = 0; mi < 4; ++mi) {
      int rr = wr*64 + mi*16 + (lane & 15);
      ah[mi] = *(const bf16x8*)&sAh[rr*BK + koff];
      if constexpr (SPLIT) al[mi] = *(const bf16x8*)&sAl[rr*BK + koff];
    }
    #pragma unroll
    for (int ni = 0; ni < 4; ++ni) {
      int rr = wc*64 + ni*16 + (lane & 15);
      bh[ni] = *(const bf16x8*)&sBh[rr*BK + koff];
      if constexpr (SPLIT) bl[ni] = *(const bf16x8*)&sBl[rr*BK + koff];
    }
    #pragma unroll
    for (int mi = 0; mi < 4; ++mi)
      #pragma unroll
      for (int ni = 0; ni < 4; ++ni) {
        acc[mi][ni] = MFMA_B16(ah[mi], bh[ni], acc[mi][ni]);
        if constexpr (SPLIT) {
          acc[mi][ni] = MFMA_B16(ah[mi], bl[ni], acc[mi][ni]);
          acc[mi][ni] = MFMA_B16(al[mi], bh[ni], acc[mi][ni]);
        }
      }
    __syncthreads();
  }

  #pragma unroll
  for (int mi = 0; mi < 4; ++mi) {
    #pragma unroll
    for (int ni = 0; ni < 4; ++ni) {
      int lrow = m0 + wr*64 + mi*16 + ((lane >> 4) << 2);
      int col = n0 + wc*64 + ni*16 + (lane & 15);
      #pragma unroll
      for (int j = 0; j < 4; ++j) {
        int rr = lrow + j;
        float v = acc[mi][ni][j];
        if constexpr (EPI == 1) {
          outb[(size_t)rr*G4c + col] = (bf16)(v + p0[col]);
        } else {
          if (rr < R && col < N) {
            int val = meta[1 + rr];
            int t = val >> 7, b = val & 127;
            outf[(size_t)b*(TMAXc*Vc) + (size_t)t*Vc + col] = v + p0[col];
          }
        }
      }
    }
  }
}

// ---------------- persistent LSTM recurrence ----------------
// 256 blocks x 256 threads, 1 block/CU. Block (strip 0..127, rh 0..1).
// NEW vs R10: (1) chain stores coalesced: epilogue -> 2KB per-wave LDS scratch
// (wave-local flush: lgkmcnt(0)+sched_barrier) -> lanes 0-31 emit 16B sc0sc1
// write-through stores (128/block vs 512 scattered 2B); (2) Hall stores from
// scratch by lanes 32-63 AFTER the flag signal, masked by lens; (3) gate-0 poll
// snapshots gates 1-3 in the same round trip -> ready gates cost one s_barrier.

__global__ __launch_bounds__(256, 1) void lstm_persist(
  const bf16* __restrict__ Whi, const bf16* __restrict__ Wlo,
  const bf16* __restrict__ Xg,
  bf16* __restrict__ hCh, bf16* __restrict__ hCl,
  bf16* __restrict__ Hh, bf16* __restrict__ Hl,
  const int* __restrict__ lens,
  int* __restrict__ flg)
{
  extern __shared__ char sWc[];    // 128 KB W (hi 0, lo +65536, swizzled) + 2 KB scratch
  int tid = threadIdx.x, lane = tid & 63, w = tid >> 6;
  int bid = blockIdx.x;
  int strip = bid >> 1, rh = bid & 1;
  int pc0 = strip * 32;
  int row0 = rh * 64 + w * 16;
  int grp = strip >> 5;
  char* scr = sWc + 131072 + w*512;   // per-wave: hi [16][8] @0, lo @256

  for (int ch = tid; ch < 4096; ch += 256) {
    int p = ch >> 7;
    int k = (ch & 127) * 8;
    bf16x8 vh = *(const bf16x8*)&Whi[(size_t)(pc0 + p)*Hc + k];
    bf16x8 vl = *(const bf16x8*)&Wlo[(size_t)(pc0 + p)*Hc + k];
    int be = (p*Hc + k)*2;
    int sw = (p & 7) << 4;
    *(bf16x8*)(sWc + (be ^ sw)) = vh;
    *(bf16x8*)(sWc + ((be + 65536) ^ sw)) = vl;
  }
  __syncthreads();

  int bp = lane & 15;
  int bk = (lane >> 4) << 3;
  int bswz = (bp & 7) << 4;
  int rbase = row0 + ((lane >> 4) << 2);
  int e = lane & 3;

  int Lh = lens[rh * 64];
  if (Lh > NSTEP) Lh = NSTEP;
  int lenv = lens[row0 + (lane & 15)] - 1;   // used by Hall lanes (32-63)

  float creg[2][4] = {};
  float xgv[2][4];
  #pragma unroll
  for (int ni = 0; ni < 2; ++ni)
    #pragma unroll
    for (int j = 0; j < 4; ++j)
      xgv[ni][j] = (float)Xg[(size_t)(rbase + j)*G4c + pc0 + ni*16 + bp];

#define GATEQ(g, fg) do { if (s > 0) { \
    if (tid == 0 && (fg) < 32) waitflag(&flg[(s*2 + rh)*4 + (g)], 32); \
    __builtin_amdgcn_s_barrier(); \
    asm volatile("" ::: "memory"); } } while (0)

#define LOADQ(qh, ql, g) do { \
    _Pragma("unroll") \
    for (int i = 0; i < 8; ++i) { \
      qh[i] = *(const bf16x8*)(pah + ((g)*8 + i)*32); \
      ql[i] = *(const bf16x8*)(pal + ((g)*8 + i)*32); \
    } \
    asm volatile("" ::: "memory"); } while (0)

#define MFMAQ(qh, ql, g) do { \
    _Pragma("unroll") \
    for (int i = 0; i < 8; ++i) { \
      int ks = (g)*8 + i; \
      _Pragma("unroll") \
      for (int ni = 0; ni < 2; ++ni) { \
        int be = ((ni*16 + bp)*Hc + ks*32 + bk)*2; \
        bf16x8 bvh = *(const bf16x8*)(sWc + (be ^ bswz)); \
        bf16x8 bvl = *(const bf16x8*)(sWc + ((be + 65536) ^ bswz)); \
        aHH[ni] = MFMA_B16(qh[i], bvh, aHH[ni]); \
        aHL[ni] = MFMA_B16(qh[i], bvl, aHL[ni]); \
        aLH[ni] = MFMA_B16(ql[i], bvh, aLH[ni]); \
      } \
    } } while (0)

  #pragma unroll 1
  for (int s = 0; s < Lh; ++s) {
    const bf16* pah = hCh + (size_t)s*Bc*Hc + (size_t)(row0 + bp)*Hc + bk;
    const bf16* pal = hCl + (size_t)s*Bc*Hc + (size_t)(row0 + bp)*Hc + bk;
    bf16* hwh = hCh + (size_t)(s+1)*Bc*Hc;
    bf16* hwl = hCl + (size_t)(s+1)*Bc*Hc;

    f32x4 aHH[2], aHL[2], aLH[2];
    #pragma unroll
    for (int ni = 0; ni < 2; ++ni) {
      #pragma unroll
      for (int j = 0; j < 4; ++j) aHH[ni][j] = xgv[ni][j];
      aHL[ni] = (f32x4){0.f,0.f,0.f,0.f};
      aLH[ni] = (f32x4){0.f,0.f,0.f,0.f};
    }

    bf16x8 qh0[8], ql0[8], qh1[8], ql1[8];
    int f1 = 32, f2 = 32, f3 = 32;

    if (s > 0) {
      if (tid == 0) waitflags4(&flg[(s*2 + rh)*4], f1, f2, f3);
      __builtin_amdgcn_s_barrier();
      asm volatile("" ::: "memory");
    }
    LOADQ(qh0, ql0, 0);
    GATEQ(1, f1); LOADQ(qh1, ql1, 1);
    MFMAQ(qh0, ql0, 0);
    GATEQ(2, f2); LOADQ(qh0, ql0, 2);
    MFMAQ(qh1, ql1, 1);
    GATEQ(3, f3); LOADQ(qh1, ql1, 3);
    MFMAQ(qh0, ql0, 2);
    MFMAQ(qh1, ql1, 3);

    // ---- LSTM epilogue: gates -> h -> per-wave LDS scratch ----
    #pragma unroll
    for (int ni = 0; ni < 2; ++ni) {
      #pragma unroll
      for (int j = 0; j < 4; ++j) {
        float v = aHH[ni][j] + aHL[ni][j] + aLH[ni][j];
        float a  = v;
        float b1 = __shfl_xor(v, 1);
        float c2 = __shfl_xor(v, 2);
        float d3 = __shfl_xor(v, 3);
        int m;
        m = e;     float gI = (m==0)?a:(m==1)?b1:(m==2)?c2:d3;
        m = e ^ 1; float gF = (m==0)?a:(m==1)?b1:(m==2)?c2:d3;
        m = e ^ 2; float gG = (m==0)?a:(m==1)?b1:(m==2)?c2:d3;
        m = e ^ 3; float gO = (m==0)?a:(m==1)?b1:(m==2)?c2:d3;

        float co = creg[ni][j];
        float cn = fsigm(gF)*co + fsigm(gI)*ftanh(gG);
        float hn = fsigm(gO)*ftanh(cn);
        creg[ni][j] = cn;
        bf16 hhi = (bf16)hn;
        int r16 = ((lane >> 4) << 2) + j;          // row in wave's 16
        int c8  = ni*4 + (bp >> 2);                // col in strip's 8
        if (e == 1)      *(bf16*)(scr + (r16*8 + c8)*2) = hhi;
        else if (e == 2) *(bf16*)(scr + 256 + (r16*8 + c8)*2) = (bf16)(hn - (float)hhi);
      }
    }

    // wave-local flush: this wave's LDS writes visible to its own lanes
    asm volatile("s_waitcnt lgkmcnt(0)" ::: "memory");
    __builtin_amdgcn_sched_barrier(0);

    // lanes 0-31: coalesced 16B write-through chain stores
    if (lane < 32) {
      int r = lane & 15, buf = lane >> 4;
      bf16x8 vv = *(const bf16x8*)(scr + buf*256 + r*16);
      bf16* dst = (buf ? hwl : hwh) + (size_t)(row0 + r)*Hc + strip*8;
      wt16(dst, vv);
    }

    __syncthreads();                 // drains chain stores for whole block
    if (tid == 0 && s + 1 < Lh)
      __hip_atomic_fetch_add(&flg[((s+1)*2 + rh)*4 + grp], 1,
                             __ATOMIC_RELAXED, __HIP_MEMORY_SCOPE_AGENT);

    // ---- off-path: Hall stores (lanes 32-63, masked) + Xg prefetch ----
    if (s > 0 && lane >= 32 && (s - 1) < lenv) {
      int r = lane & 15, buf = (lane >> 4) & 1;
      bf16x8 vv = *(const bf16x8*)(scr + buf*256 + r*16);
      *(bf16x8*)((buf ? Hl : Hh) + (size_t)((s-1)*Bc + row0 + r)*Hc + strip*8) = vv;
    }
    if (s + 1 < Lh) {
      #pragma unroll
      for (int ni = 0; ni < 2; ++ni)
        #pragma unroll
        for (int j = 0; j < 4; ++j)
          xgv[ni][j] = (float)Xg[(size_t)((s+1)*Bc + rbase + j)*G4c + pc0 + ni*16 + bp];
    }
  }
#undef GATEQ
#undef LOADQ
#undef MFMAQ
}

// ---------------- launch ----------------

extern "C" void kernel_launch(void* const* d_in, const int* in_sizes, int n_in,
                              void* d_out, int out_size, void* d_ws, size_t ws_size,
                              hipStream_t stream)
{
  const float* enc   = (const float*)d_in[0];
  const int*   gt    = (const int*)  d_in[1];
  const int*   lens  = (const int*)  d_in[2];
  const float* emb   = (const float*)d_in[3];
  const float* Winit = (const float*)d_in[4];
  const float* binit = (const float*)d_in[5];
  const float* gam   = (const float*)d_in[6];
  const float* bet   = (const float*)d_in[7];
  const float* Wih   = (const float*)d_in[8];
  const float* bih   = (const float*)d_in[9];
  const float* Whh   = (const float*)d_in[10];
  const float* bhh   = (const float*)d_in[11];
  const float* Wfc   = (const float*)d_in[12];
  const float* bfc   = (const float*)d_in[13];
  float* out = (float*)d_out;

  char* ws = (char*)d_ws;
  size_t off = 0;
  auto alloc = [&](size_t bytes) -> char* {
    char* p = ws + off;
    off += (bytes + 255) & ~(size_t)255;
    return p;
  };

  bf16* featB  = (bf16*)alloc((size_t)Bc*Fc*2);
  bf16* WinitB = (bf16*)alloc((size_t)Ec*Fc*2);
  bf16* WihpB  = (bf16*)alloc((size_t)G4c*Ec*2);
  bf16* WhhHi  = (bf16*)alloc((size_t)G4c*Hc*2);
  bf16* WhhLo  = (bf16*)alloc((size_t)G4c*Hc*2);
  bf16* WfcHi  = (bf16*)alloc((size_t)Vc*Hc*2);
  bf16* WfcLo  = (bf16*)alloc((size_t)Vc*Hc*2);
  float* bcomb = (float*)alloc((size_t)G4c*4);
  bf16* Xall   = (bf16*)alloc((size_t)MALLc*Ec*2);
  bf16* Xg     = (bf16*)alloc((size_t)MALLc*G4c*2);
  bf16* hChH   = (bf16*)alloc((size_t)(NSTEP+1)*Bc*Hc*2);
  bf16* hChL   = (bf16*)alloc((size_t)(NSTEP+1)*Bc*Hc*2);
  bf16* HallH  = (bf16*)alloc((size_t)MOUTc*Hc*2);
  bf16* HallL  = (bf16*)alloc((size_t)MOUTc*Hc*2);
  float* part  = (float*)alloc((size_t)8*128*512*4);
  int*  meta   = (int*) alloc((size_t)(1 + MOUTc)*4);
  int*  flg    = (int*) alloc((size_t)256*4);

  if (off > ws_size) return;

  hipMemsetAsync(hChH, 0, (size_t)Bc*Hc*2, stream);
  hipMemsetAsync(hChL, 0, (size_t)Bc*Hc*2, stream);
  hipMemsetAsync(flg, 0, (size_t)256*4, stream);

  mean_kernel<<<256, 256, 0, stream>>>(enc, featB);
  conv_kernel<<<(Ec*Fc/4 + 255)/256, 256, 0, stream>>>(Winit, WinitB, Ec*Fc/4);
  permconv_ih<<<(G4c*Ec/4 + 255)/256, 256, 0, stream>>>(Wih, WihpB);
  permsplit_hh<<<(G4c*Hc/4 + 255)/256, 256, 0, stream>>>(Whh, WhhHi, WhhLo);
  split_kernel<<<(Vc*Hc/4 + 255)/256, 256, 0, stream>>>(Wfc, WfcHi, WfcLo, Vc*Hc/4);
  bcomb_kernel<<<(G4c + 255)/256, 256, 0, stream>>>(bih, bhh, bcomb);
  gather_kernel<<<(MOUTc*(Ec/4) + 255)/256, 256, 0, stream>>>(emb, gt, Xall);
  build_ridx<<<(MOUTc + 255)/256, 256, 0, stream>>>(lens, meta);
  zerofill<<<(MOUTc*2500 + 255)/256, 256, 0, stream>>>(lens, out);

  initA<<<32, 256, 0, stream>>>(featB, WinitB, part);
  initB<<<(128*512 + 255)/256, 256, 0, stream>>>(part, binit, gam, bet, Xall);

  gemm_kernel<1,false,true><<<31*32, 256, 0, stream>>>(
      Xall, nullptr, WihpB, nullptr, MALLc, G4c, Ec, 31,
      bcomb, Xg, nullptr, nullptr);

  hipFuncSetAttribute(reinterpret_cast<const void*>(lstm_persist),
                      hipFuncAttributeMaxDynamicSharedMemorySize, 133120);
  lstm_persist<<<NBLK, 256, 133120, stream>>>(
      WhhHi, WhhLo, Xg, hChH, hChL, HallH, HallL, lens, flg);

  gemm_kernel<2,true,true><<<79*30, 256, 0, stream>>>(
      HallH, HallL, WfcHi, WfcLo, MOUTc, Vc, Hc, 30,
      bfc, nullptr, out, meta);
}

// Round 12
// 646.043 us; speedup vs baseline: 1.5874x; 1.1451x over previous
//
#include <hip/hip_runtime.h>
#include <math.h>

typedef __bf16 bf16;
typedef __bf16 bf16x8 __attribute__((ext_vector_type(8)));
typedef __bf16 bf16x4 __attribute__((ext_vector_type(4)));
typedef float f32x4 __attribute__((ext_vector_type(4)));

#define MFMA_B16(a,b,c) __builtin_amdgcn_mfma_f32_16x16x32_bf16((a),(b),(c),0,0,0)

constexpr int TMAXc = 30;
constexpr int Bc = 128, Pc = 196, Fc = 2048, Ec = 512, Hc = 1024, Vc = 10000;
constexpr int G4c = 4 * Hc;          // 4096
constexpr int NSTEP = TMAXc + 1;     // 31
constexpr int MALLc = NSTEP * Bc;    // 3968
constexpr int MOUTc = TMAXc * Bc;    // 3840
constexpr int NBLK = 256;            // persistent kernel grid

__device__ __forceinline__ float fsigm(float x){
  return __fdividef(1.0f, 1.0f + __expf(-x));
}
__device__ __forceinline__ float ftanh(float x){
  return 1.0f - __fdividef(2.0f, __expf(2.0f*x) + 1.0f);
}
// 4-way select by runtime index (3 cndmask, no scratch - rule #20 safe)
__device__ __forceinline__ float sel4(float a, float b, float c, float d, int i){
  float x = (i & 1) ? b : a;
  float y = (i & 1) ? d : c;
  return (i & 2) ? y : x;
}

__device__ __forceinline__ void gll16(const void* g, void* l){
  __builtin_amdgcn_global_load_lds((const __attribute__((address_space(1))) void*)g,
                                   (__attribute__((address_space(3))) void*)l, 16, 0, 0);
}

// 16B write-through store (bypasses L1/L2, lands at coherence point / MALL)
__device__ __forceinline__ void wt16(bf16* p, bf16x8 v){
  asm volatile("global_store_dwordx4 %0, %1, off sc0 sc1" :: "v"(p), "v"(v) : "memory");
}

__device__ __forceinline__ int aldf(int* f){
  return __hip_atomic_load(f, __ATOMIC_RELAXED, __HIP_MEMORY_SCOPE_AGENT);
}

// bounded spin: escapes after ~1ms (s_memrealtime = 100 MHz const clock)
__device__ __forceinline__ void waitflag(int* f, int tgt){
  long long t0 = __builtin_amdgcn_s_memrealtime();
  while (aldf(f) < tgt) {
    __builtin_amdgcn_s_sleep(1);
    if (__builtin_amdgcn_s_memrealtime() - t0 > 100000) break;
  }
}

// poll gate0 while snapshotting gates 1-3 in the same round trip
__device__ __forceinline__ void waitflags4(int* F, int& f1, int& f2, int& f3){
  long long t0 = __builtin_amdgcn_s_memrealtime();
  for (;;) {
    int f0 = aldf(F + 0);
    f1 = aldf(F + 1);
    f2 = aldf(F + 2);
    f3 = aldf(F + 3);
    if (f0 >= 32) break;
    __builtin_amdgcn_s_sleep(1);
    if (__builtin_amdgcn_s_memrealtime() - t0 > 100000) break;
  }
}

// ---------------- prep kernels ----------------

__global__ void mean_kernel(const float* __restrict__ enc, bf16* __restrict__ feat){
  int blk = blockIdx.x, b = blk >> 1, half = blk & 1;
  int f0 = half*1024 + threadIdx.x*4;
  const float* p = enc + (size_t)b*Pc*Fc + f0;
  float4 s = {0.f,0.f,0.f,0.f};
  #pragma unroll 4
  for (int q = 0; q < Pc; ++q) {
    float4 v = *(const float4*)(p + (size_t)q*Fc);
    s.x += v.x; s.y += v.y; s.z += v.z; s.w += v.w;
  }
  const float r = 1.0f/(float)Pc;
  bf16x4 o = { (bf16)(s.x*r), (bf16)(s.y*r), (bf16)(s.z*r), (bf16)(s.w*r) };
  *(bf16x4*)&feat[b*Fc + f0] = o;
}

__global__ void conv_kernel(const float* __restrict__ src, bf16* __restrict__ dst, int n4){
  int i = blockIdx.x*256 + threadIdx.x;
  if (i >= n4) return;
  float4 v = ((const float4*)src)[i];
  bf16x4 o = { (bf16)v.x, (bf16)v.y, (bf16)v.z, (bf16)v.w };
  *(bf16x4*)&dst[i*4] = o;
}

__global__ void permconv_ih(const float* __restrict__ W, bf16* __restrict__ Wp){
  int i = blockIdx.x*256 + threadIdx.x;
  if (i >= G4c*Ec/4) return;
  int i4 = i*4;
  int rp = i4 >> 9, k = i4 & 511;
  int g = rp & 3, j = rp >> 2;
  float4 v = *(const float4*)&W[(size_t)(g*Hc + j)*Ec + k];
  bf16x4 o = { (bf16)v.x, (bf16)v.y, (bf16)v.z, (bf16)v.w };
  *(bf16x4*)&Wp[i4] = o;
}

__global__ void permsplit_hh(const float* __restrict__ W, bf16* __restrict__ Whi, bf16* __restrict__ Wlo){
  int i = blockIdx.x*256 + threadIdx.x;
  if (i >= G4c*Hc/4) return;
  int i4 = i*4;
  int rp = i4 >> 10, k = i4 & 1023;
  int g = rp & 3, j = rp >> 2;
  float4 v = *(const float4*)&W[(size_t)(g*Hc + j)*Hc + k];
  bf16 h0=(bf16)v.x, h1=(bf16)v.y, h2=(bf16)v.z, h3=(bf16)v.w;
  bf16x4 hi = { h0, h1, h2, h3 };
  bf16x4 lo = { (bf16)(v.x-(float)h0), (bf16)(v.y-(float)h1), (bf16)(v.z-(float)h2), (bf16)(v.w-(float)h3) };
  *(bf16x4*)&Whi[i4] = hi;
  *(bf16x4*)&Wlo[i4] = lo;
}

__global__ void split_kernel(const float* __restrict__ W, bf16* __restrict__ Whi, bf16* __restrict__ Wlo, int n4){
  int i = blockIdx.x*256 + threadIdx.x;
  if (i >= n4) return;
  float4 v = ((const float4*)W)[i];
  bf16 h0=(bf16)v.x, h1=(bf16)v.y, h2=(bf16)v.z, h3=(bf16)v.w;
  bf16x4 hi = { h0, h1, h2, h3 };
  bf16x4 lo = { (bf16)(v.x-(float)h0), (bf16)(v.y-(float)h1), (bf16)(v.z-(float)h2), (bf16)(v.w-(float)h3) };
  *(bf16x4*)&Whi[i*4] = hi;
  *(bf16x4*)&Wlo[i*4] = lo;
}

__global__ void bcomb_kernel(const float* __restrict__ bih, const float* __restrict__ bhh, float* __restrict__ bc){
  int i = blockIdx.x*256 + threadIdx.x;
  if (i >= G4c) return;
  int g = i & 3, j = i >> 2;
  bc[i] = bih[g*Hc + j] + bhh[g*Hc + j];
}

__global__ void gather_kernel(const float* __restrict__ emb, const int* __restrict__ gt, bf16* __restrict__ X){
  int idx = blockIdx.x*256 + threadIdx.x;
  if (idx >= MOUTc*(Ec/4)) return;
  int r = idx >> 7, ei = (idx & 127) * 4;
  int s = (r >> 7) + 1, b = r & 127;
  int tok = gt[b*(TMAXc+1) + (s-1)];
  float4 v = *(const float4*)(emb + (size_t)tok*Ec + ei);
  bf16x4 o = { (bf16)v.x, (bf16)v.y, (bf16)v.z, (bf16)v.w };
  *(bf16x4*)&X[(size_t)(s*Bc + b)*Ec + ei] = o;
}

__global__ void build_ridx(const int* __restrict__ lens, int* __restrict__ meta){
  int i = blockIdx.x*256 + threadIdx.x;
  if (i >= MOUTc) return;
  int t = i >> 7, b = i & 127;
  int S = 0, R = 0;
  for (int bb = 0; bb < 128; ++bb) {
    int l = lens[bb] - 1;
    S += (t < l) ? t : l;
    R += l;
  }
  if (i == 0) meta[0] = R;
  if (i >= R) meta[1 + i] = 0;
  if (t < lens[b] - 1) meta[1 + S + b] = i;
}

__global__ void zerofill(const int* __restrict__ lens, float* __restrict__ out){
  int i = blockIdx.x*256 + threadIdx.x;
  if (i >= MOUTc*2500) return;
  int row = i / 2500, c4 = i - row*2500;
  int b = row / TMAXc, t = row - b*TMAXc;
  if (t >= lens[b] - 1) {
    float4 z = {0.f,0.f,0.f,0.f};
    *(float4*)(out + (size_t)row*Vc + c4*4) = z;
  }
}

// ---------------- GEMM A split-K: x0 partials (32 blocks = 4 ntiles x 8 kchunks) ----------
__global__ __launch_bounds__(256, 2) void initA(
  const bf16* __restrict__ feat, const bf16* __restrict__ Wi, float* __restrict__ part)
{
  __shared__ alignas(16) bf16 sA[128*32], sB[128*32];
  int tid = threadIdx.x, lane = tid & 63, w = tid >> 6, wr = w >> 1, wc = w & 1;
  int nt = blockIdx.x & 3, kc = blockIdx.x >> 2;
  int n0 = nt*128;

  f32x4 acc[4][4] = {};
  for (int kt = kc*256; kt < kc*256 + 256; kt += 32) {
    #pragma unroll
    for (int is = 0; is < 2; ++is) {
      int p = tid*16 + is*4096;
      int r = p >> 6, c = (p & 63) >> 1;
      int ldsoff = w*512 + is*2048;
      gll16(feat + (size_t)r*Fc + kt + c, &sA[ldsoff]);
      gll16(Wi + (size_t)(n0 + r)*Fc + kt + c, &sB[ldsoff]);
    }
    __syncthreads();
    int koff = (lane >> 4) * 8;
    bf16x8 ah[4], bh[4];
    #pragma unroll
    for (int mi = 0; mi < 4; ++mi)
      ah[mi] = *(const bf16x8*)&sA[(wr*64 + mi*16 + (lane & 15))*32 + koff];
    #pragma unroll
    for (int ni = 0; ni < 4; ++ni)
      bh[ni] = *(const bf16x8*)&sB[(wc*64 + ni*16 + (lane & 15))*32 + koff];
    #pragma unroll
    for (int mi = 0; mi < 4; ++mi)
      #pragma unroll
      for (int ni = 0; ni < 4; ++ni)
        acc[mi][ni] = MFMA_B16(ah[mi], bh[ni], acc[mi][ni]);
    __syncthreads();
  }
  #pragma unroll
  for (int mi = 0; mi < 4; ++mi)
    #pragma unroll
    for (int ni = 0; ni < 4; ++ni) {
      int lrow = wr*64 + mi*16 + ((lane >> 4) << 2);
      int col = n0 + wc*64 + ni*16 + (lane & 15);
      #pragma unroll
      for (int j = 0; j < 4; ++j)
        part[((size_t)kc*128 + lrow + j)*512 + col] = acc[mi][ni][j];
    }
}

__global__ void initB(const float* __restrict__ part, const float* __restrict__ binit,
                      const float* __restrict__ gam, const float* __restrict__ bet,
                      bf16* __restrict__ Xall)
{
  int i = blockIdx.x*256 + threadIdx.x;
  if (i >= 128*512) return;
  int col = i & 511;
  float v = 0.f;
  #pragma unroll
  for (int kc = 0; kc < 8; ++kc) v += part[(size_t)kc*128*512 + i];
  const float rbn = rsqrtf(1.0f + 1e-5f);
  v = fsigm(v + binit[col]);
  v = gam[col]*(v*rbn) + bet[col];
  Xall[i] = (bf16)v;
}

// ---------------- generic MFMA GEMM (128x128 tile, BK=32, nt-major, XCD swizzle) --------
template<int EPI, bool SPLIT, bool XSWZ>
__global__ __launch_bounds__(256, 2) void gemm_kernel(
  const bf16* __restrict__ Ahi, const bf16* __restrict__ Alo,
  const bf16* __restrict__ Bhi, const bf16* __restrict__ Blo,
  int M, int N, int K, int mtiles,
  const float* __restrict__ p0,
  bf16* __restrict__ outb, float* __restrict__ outf, const int* __restrict__ meta)
{
  constexpr int BK = 32;
  __shared__ alignas(16) bf16 sAh[128*BK], sBh[128*BK];
  __shared__ alignas(16) bf16 sAl[SPLIT ? 128*BK : 8], sBl[SPLIT ? 128*BK : 8];

  int tid = threadIdx.x;
  int lane = tid & 63, w = tid >> 6, wr = w >> 1, wc = w & 1;
  int bid = blockIdx.x;
  if constexpr (XSWZ) {
    int nwg = gridDim.x, q = nwg >> 3, r = nwg & 7;
    int x = bid & 7, o = bid >> 3;
    bid = (x < r ? x*(q+1) : r*(q+1) + (x-r)*q) + o;
  }
  int nt = bid / mtiles, mt = bid - nt*mtiles;
  int m0 = mt*128, n0 = nt*128;

  int R = M;
  if constexpr (EPI == 2) {
    R = meta[0];
    if (m0 >= R) return;
  }

  int sr = (tid*16) >> 6;
  int gr0, gr1;
  if constexpr (EPI == 2) { gr0 = meta[1 + m0 + sr]; gr1 = meta[1 + m0 + sr + 64]; }
  else                    { gr0 = m0 + sr;           gr1 = m0 + sr + 64; }

  f32x4 acc[4][4] = {};

  for (int kt = 0; kt < K; kt += BK) {
    #pragma unroll
    for (int is = 0; is < 2; ++is) {
      int p = tid*16 + is*4096;
      int r = p >> 6, c = (p & 63) >> 1;
      int ldsoff = w*512 + is*2048;
      int ga = is ? gr1 : gr0;
      gll16(Ahi + (size_t)ga*K + kt + c, &sAh[ldsoff]);
      int rb = n0 + r; rb = rb < N ? rb : N - 1;
      gll16(Bhi + (size_t)rb*K + kt + c, &sBh[ldsoff]);
      if constexpr (SPLIT) {
        gll16(Alo + (size_t)ga*K + kt + c, &sAl[ldsoff]);
        gll16(Blo + (size_t)rb*K + kt + c, &sBl[ldsoff]);
      }
    }
    __syncthreads();

    int koff = (lane >> 4) * 8;
    bf16x8 ah[4], bh[4], al[SPLIT?4:1], bl[SPLIT?4:1];
    #pragma unroll
    for (int mi = 0; mi < 4; ++mi) {
      int rr = wr*64 + mi*16 + (lane & 15);
      ah[mi] = *(const bf16x8*)&sAh[rr*BK + koff];
      if constexpr (SPLIT) al[mi] = *(const bf16x8*)&sAl[rr*BK + koff];
    }
    #pragma unroll
    for (int ni = 0; ni < 4; ++ni) {
      int rr = wc*64 + ni*16 + (lane & 15);
      bh[ni] = *(const bf16x8*)&sBh[rr*BK + koff];
      if constexpr (SPLIT) bl[ni] = *(const bf16x8*)&sBl[rr*BK + koff];
    }
    #pragma unroll
    for (int mi = 0; mi < 4; ++mi)
      #pragma unroll
      for (int ni = 0; ni < 4; ++ni) {
        acc[mi][ni] = MFMA_B16(ah[mi], bh[ni], acc[mi][ni]);
        if constexpr (SPLIT) {
          acc[mi][ni] = MFMA_B16(ah[mi], bl[ni], acc[mi][ni]);
          acc[mi][ni] = MFMA_B16(al[mi], bh[ni], acc[mi][ni]);
        }
      }
    __syncthreads();
  }

  #pragma unroll
  for (int mi = 0; mi < 4; ++mi) {
    #pragma unroll
    for (int ni = 0; ni < 4; ++ni) {
      int lrow = m0 + wr*64 + mi*16 + ((lane >> 4) << 2);
      int col = n0 + wc*64 + ni*16 + (lane & 15);
      #pragma unroll
      for (int j = 0; j < 4; ++j) {
        int rr = lrow + j;
        float v = acc[mi][ni][j];
        if constexpr (EPI == 1) {
          outb[(size_t)rr*G4c + col] = (bf16)(v + p0[col]);
        } else {
          if (rr < R && col < N) {
            int val = meta[1 + rr];
            int t = val >> 7, b = val & 127;
            outf[(size_t)b*(TMAXc*Vc) + (size_t)t*Vc + col] = v + p0[col];
          }
        }
      }
    }
  }
}

// ---------------- persistent LSTM recurrence ----------------
// 256 blocks x 256 threads, 1 block/CU. Block (strip 0..127, rh 0..1).
// NEW vs R11 (no sync changes): (1) W LDS layout = per-(ks,ni) 1KB chunks so every
// MFMA B-read is a LINEAR 64-lane x 16B burst (zero bank conflicts, immediate offsets,
// no XOR math); (2) epilogue lane-specialized: quad lane e computes only row j=e
// (shfl rounds pass v[e^m]) -> transcendental VALU / 4, creg 8->2.

__global__ __launch_bounds__(256, 1) void lstm_persist(
  const bf16* __restrict__ Whi, const bf16* __restrict__ Wlo,
  const bf16* __restrict__ Xg,
  bf16* __restrict__ hCh, bf16* __restrict__ hCl,
  bf16* __restrict__ Hh, bf16* __restrict__ Hl,
  const int* __restrict__ lens,
  int* __restrict__ flg)
{
  extern __shared__ char sWc[];    // 64KB hi chunks + 64KB lo chunks + 2KB scratch
  int tid = threadIdx.x, lane = tid & 63, w = tid >> 6;
  int bid = blockIdx.x;
  int strip = bid >> 1, rh = bid & 1;
  int pc0 = strip * 32;
  int row0 = rh * 64 + w * 16;
  int grp = strip >> 5;
  char* scr = sWc + 131072 + w*512;   // per-wave: hi [16][8] @0, lo @256

  // ---- fill W slice into LDS: chunk (ks,ni) holds lanes' fragments linearly ----
  // element W[pc0 + ni*16 + bp][ks*32 + kg*8 + t] -> sWc[((ks*2+ni)*64 + kg*16 + bp)*16 + t*2]
  for (int ch = tid; ch < 4096; ch += 256) {
    int p = ch >> 7;              // 0..31 = ni*16 + bp
    int k = (ch & 127) * 8;       // 0..1016
    int ni = p >> 4, bp = p & 15;
    int ks = k >> 5, kg = (k >> 3) & 3;
    int off = (((ks*2 + ni)*4 + kg)*16 + bp) * 16;
    bf16x8 vh = *(const bf16x8*)&Whi[(size_t)(pc0 + p)*Hc + k];
    bf16x8 vl = *(const bf16x8*)&Wlo[(size_t)(pc0 + p)*Hc + k];
    *(bf16x8*)(sWc + off) = vh;
    *(bf16x8*)(sWc + 65536 + off) = vl;
  }
  __syncthreads();

  int bp = lane & 15;
  int bk = (lane >> 4) << 3;
  int rbase = row0 + ((lane >> 4) << 2);
  int e = lane & 3;
  const char* sWhiB = sWc + lane*16;           // linear per-lane base (hi)
  const char* sWloB = sWc + 65536 + lane*16;   // (lo)

  int Lh = lens[rh * 64];
  if (Lh > NSTEP) Lh = NSTEP;
  int lenv = lens[row0 + (lane & 15)] - 1;   // used by Hall lanes (32-63)

  float creg[2] = {0.f, 0.f};     // c-state: this lane owns rows rbase+e only
  float xgv[2][4];
  #pragma unroll
  for (int ni = 0; ni < 2; ++ni)
    #pragma unroll
    for (int j = 0; j < 4; ++j)
      xgv[ni][j] = (float)Xg[(size_t)(rbase + j)*G4c + pc0 + ni*16 + bp];

#define GATEQ(g, fg) do { if (s > 0) { \
    if (tid == 0 && (fg) < 32) waitflag(&flg[(s*2 + rh)*4 + (g)], 32); \
    __builtin_amdgcn_s_barrier(); \
    asm volatile("" ::: "memory"); } } while (0)

#define LOADQ(qh, ql, g) do { \
    _Pragma("unroll") \
    for (int i = 0; i < 8; ++i) { \
      qh[i] = *(const bf16x8*)(pah + ((g)*8 + i)*32); \
      ql[i] = *(const bf16x8*)(pal + ((g)*8 + i)*32); \
    } \
    asm volatile("" ::: "memory"); } while (0)

#define MFMAQ(qh, ql, g) do { \
    _Pragma("unroll") \
    for (int i = 0; i < 8; ++i) { \
      int ks = (g)*8 + i; \
      _Pragma("unroll") \
      for (int ni = 0; ni < 2; ++ni) { \
        bf16x8 bvh = *(const bf16x8*)(sWhiB + (ks*2 + ni)*1024); \
        bf16x8 bvl = *(const bf16x8*)(sWloB + (ks*2 + ni)*1024); \
        aHH[ni] = MFMA_B16(qh[i], bvh, aHH[ni]); \
        aHL[ni] = MFMA_B16(qh[i], bvl, aHL[ni]); \
        aLH[ni] = MFMA_B16(ql[i], bvh, aLH[ni]); \
      } \
    } } while (0)

  #pragma unroll 1
  for (int s = 0; s < Lh; ++s) {
    const bf16* pah = hCh + (size_t)s*Bc*Hc + (size_t)(row0 + bp)*Hc + bk;
    const bf16* pal = hCl + (size_t)s*Bc*Hc + (size_t)(row0 + bp)*Hc + bk;
    bf16* hwh = hCh + (size_t)(s+1)*Bc*Hc;
    bf16* hwl = hCl + (size_t)(s+1)*Bc*Hc;

    f32x4 aHH[2], aHL[2], aLH[2];
    #pragma unroll
    for (int ni = 0; ni < 2; ++ni) {
      #pragma unroll
      for (int j = 0; j < 4; ++j) aHH[ni][j] = xgv[ni][j];
      aHL[ni] = (f32x4){0.f,0.f,0.f,0.f};
      aLH[ni] = (f32x4){0.f,0.f,0.f,0.f};
    }

    bf16x8 qh0[8], ql0[8], qh1[8], ql1[8];
    int f1 = 32, f2 = 32, f3 = 32;

    if (s > 0) {
      if (tid == 0) waitflags4(&flg[(s*2 + rh)*4], f1, f2, f3);
      __builtin_amdgcn_s_barrier();
      asm volatile("" ::: "memory");
    }
    LOADQ(qh0, ql0, 0);
    GATEQ(1, f1); LOADQ(qh1, ql1, 1);
    MFMAQ(qh0, ql0, 0);
    GATEQ(2, f2); LOADQ(qh0, ql0, 2);
    MFMAQ(qh1, ql1, 1);
    GATEQ(3, f3); LOADQ(qh1, ql1, 3);
    MFMAQ(qh0, ql0, 2);
    MFMAQ(qh1, ql1, 3);

    // ---- lane-specialized LSTM epilogue: lane e owns row rbase+e ----
    #pragma unroll
    for (int ni = 0; ni < 2; ++ni) {
      float v0 = aHH[ni][0] + aHL[ni][0] + aLH[ni][0];
      float v1 = aHH[ni][1] + aHL[ni][1] + aLH[ni][1];
      float v2 = aHH[ni][2] + aHL[ni][2] + aLH[ni][2];
      float v3 = aHH[ni][3] + aHL[ni][3] + aLH[ni][3];
      // round m: pass v[e^m]; lane e receives gate (e^m) of row e
      float g0 = sel4(v0, v1, v2, v3, e);
      float g1 = __shfl_xor(sel4(v0, v1, v2, v3, e ^ 1), 1);
      float g2 = __shfl_xor(sel4(v0, v1, v2, v3, e ^ 2), 2);
      float g3 = __shfl_xor(sel4(v0, v1, v2, v3, e ^ 3), 3);
      // gate q = received g_m with m = e^q
      float gI = sel4(g0, g1, g2, g3, e);
      float gF = sel4(g0, g1, g2, g3, e ^ 1);
      float gG = sel4(g0, g1, g2, g3, e ^ 2);
      float gO = sel4(g0, g1, g2, g3, e ^ 3);

      float co = creg[ni];
      float cn = fsigm(gF)*co + fsigm(gI)*ftanh(gG);
      float hn = fsigm(gO)*ftanh(cn);
      creg[ni] = cn;
      bf16 hhi = (bf16)hn;
      int r16 = ((lane >> 4) << 2) + e;   // row in wave's 16
      int c8  = ni*4 + (bp >> 2);         // col in strip's 8
      *(bf16*)(scr + (r16*8 + c8)*2) = hhi;
      *(bf16*)(scr + 256 + (r16*8 + c8)*2) = (bf16)(hn - (float)hhi);
    }

    // wave-local flush: this wave's LDS writes visible to its own lanes
    asm volatile("s_waitcnt lgkmcnt(0)" ::: "memory");
    __builtin_amdgcn_sched_barrier(0);

    // lanes 0-31: coalesced 16B write-through chain stores
    if (lane < 32) {
      int r = lane & 15, buf = lane >> 4;
      bf16x8 vv = *(const bf16x8*)(scr + buf*256 + r*16);
      bf16* dst = (buf ? hwl : hwh) + (size_t)(row0 + r)*Hc + strip*8;
      wt16(dst, vv);
    }

    __syncthreads();                 // drains chain stores for whole block
    if (tid == 0 && s + 1 < Lh)
      __hip_atomic_fetch_add(&flg[((s+1)*2 + rh)*4 + grp], 1,
                             __ATOMIC_RELAXED, __HIP_MEMORY_SCOPE_AGENT);

    // ---- off-path: Hall stores (lanes 32-63, masked) + Xg prefetch ----
    if (s > 0 && lane >= 32 && (s - 1) < lenv) {
      int r = lane & 15, buf = (lane >> 4) & 1;
      bf16x8 vv = *(const bf16x8*)(scr + buf*256 + r*16);
      *(bf16x8*)((buf ? Hl : Hh) + (size_t)((s-1)*Bc + row0 + r)*Hc + strip*8) = vv;
    }
    if (s + 1 < Lh) {
      #pragma unroll
      for (int ni = 0; ni < 2; ++ni)
        #pragma unroll
        for (int j = 0; j < 4; ++j)
          xgv[ni][j] = (float)Xg[(size_t)((s+1)*Bc + rbase + j)*G4c + pc0 + ni*16 + bp];
    }
  }
#undef GATEQ
#undef LOADQ
#undef MFMAQ
}

// ---------------- launch ----------------

extern "C" void kernel_launch(void* const* d_in, const int* in_sizes, int n_in,
                              void* d_out, int out_size, void* d_ws, size_t ws_size,
                              hipStream_t stream)
{
  const float* enc   = (const float*)d_in[0];
  const int*   gt    = (const int*)  d_in[1];
  const int*   lens  = (const int*)  d_in[2];
  const float* emb   = (const float*)d_in[3];
  const float* Winit = (const float*)d_in[4];
  const float* binit = (const float*)d_in[5];
  const float* gam   = (const float*)d_in[6];
  const float* bet   = (const float*)d_in[7];
  const float* Wih   = (const float*)d_in[8];
  const float* bih   = (const float*)d_in[9];
  const float* Whh   = (const float*)d_in[10];
  const float* bhh   = (const float*)d_in[11];
  const float* Wfc   = (const float*)d_in[12];
  const float* bfc   = (const float*)d_in[13];
  float* out = (float*)d_out;

  char* ws = (char*)d_ws;
  size_t off = 0;
  auto alloc = [&](size_t bytes) -> char* {
    char* p = ws + off;
    off += (bytes + 255) & ~(size_t)255;
    return p;
  };

  bf16* featB  = (bf16*)alloc((size_t)Bc*Fc*2);
  bf16* WinitB = (bf16*)alloc((size_t)Ec*Fc*2);
  bf16* WihpB  = (bf16*)alloc((size_t)G4c*Ec*2);
  bf16* WhhHi  = (bf16*)alloc((size_t)G4c*Hc*2);
  bf16* WhhLo  = (bf16*)alloc((size_t)G4c*Hc*2);
  bf16* WfcHi  = (bf16*)alloc((size_t)Vc*Hc*2);
  bf16* WfcLo  = (bf16*)alloc((size_t)Vc*Hc*2);
  float* bcomb = (float*)alloc((size_t)G4c*4);
  bf16* Xall   = (bf16*)alloc((size_t)MALLc*Ec*2);
  bf16* Xg     = (bf16*)alloc((size_t)MALLc*G4c*2);
  bf16* hChH   = (bf16*)alloc((size_t)(NSTEP+1)*Bc*Hc*2);
  bf16* hChL   = (bf16*)alloc((size_t)(NSTEP+1)*Bc*Hc*2);
  bf16* HallH  = (bf16*)alloc((size_t)MOUTc*Hc*2);
  bf16* HallL  = (bf16*)alloc((size_t)MOUTc*Hc*2);
  float* part  = (float*)alloc((size_t)8*128*512*4);
  int*  meta   = (int*) alloc((size_t)(1 + MOUTc)*4);
  int*  flg    = (int*) alloc((size_t)256*4);

  if (off > ws_size) return;

  hipMemsetAsync(hChH, 0, (size_t)Bc*Hc*2, stream);
  hipMemsetAsync(hChL, 0, (size_t)Bc*Hc*2, stream);
  hipMemsetAsync(flg, 0, (size_t)256*4, stream);

  mean_kernel<<<256, 256, 0, stream>>>(enc, featB);
  conv_kernel<<<(Ec*Fc/4 + 255)/256, 256, 0, stream>>>(Winit, WinitB, Ec*Fc/4);
  permconv_ih<<<(G4c*Ec/4 + 255)/256, 256, 0, stream>>>(Wih, WihpB);
  permsplit_hh<<<(G4c*Hc/4 + 255)/256, 256, 0, stream>>>(Whh, WhhHi, WhhLo);
  split_kernel<<<(Vc*Hc/4 + 255)/256, 256, 0, stream>>>(Wfc, WfcHi, WfcLo, Vc*Hc/4);
  bcomb_kernel<<<(G4c + 255)/256, 256, 0, stream>>>(bih, bhh, bcomb);
  gather_kernel<<<(MOUTc*(Ec/4) + 255)/256, 256, 0, stream>>>(emb, gt, Xall);
  build_ridx<<<(MOUTc + 255)/256, 256, 0, stream>>>(lens, meta);
  zerofill<<<(MOUTc*2500 + 255)/256, 256, 0, stream>>>(lens, out);

  initA<<<32, 256, 0, stream>>>(featB, WinitB, part);
  initB<<<(128*512 + 255)/256, 256, 0, stream>>>(part, binit, gam, bet, Xall);

  gemm_kernel<1,false,true><<<31*32, 256, 0, stream>>>(
      Xall, nullptr, WihpB, nullptr, MALLc, G4c, Ec, 31,
      bcomb, Xg, nullptr, nullptr);

  hipFuncSetAttribute(reinterpret_cast<const void*>(lstm_persist),
                      hipFuncAttributeMaxDynamicSharedMemorySize, 133120);
  lstm_persist<<<NBLK, 256, 133120, stream>>>(
      WhhHi, WhhLo, Xg, hChH, hChL, HallH, HallL, lens, flg);

  gemm_kernel<2,true,true><<<79*30, 256, 0, stream>>>(
      HallH, HallL, WfcHi, WfcLo, MOUTc, Vc, Hc, 30,
      bfc, nullptr, out, meta);
}